// Round 7
// baseline (886.131 us; speedup 1.0000x reference)
//
#include <hip/hip_runtime.h>
#include <hip/hip_bf16.h>

#define HW 128
#define HW2 16384
#define NEG 0.2f

typedef __attribute__((ext_vector_type(8))) short short8;
typedef __attribute__((ext_vector_type(4))) float f32x4;

__device__ __forceinline__ float lrelu(float v) { return v >= 0.f ? v : NEG * v; }
__device__ __forceinline__ unsigned short f2bf(float f) {
    unsigned int u = __float_as_uint(f);
    u = (u + 0x7fffu + ((u >> 16) & 1u)) >> 16;
    return (unsigned short)u;
}
__device__ __forceinline__ unsigned int pk2(float a, float b) {
    __hip_bfloat162 h = __float22bfloat162_rn(float2{a, b});
    return *(unsigned int*)&h;
}
__device__ __forceinline__ float2 upk(unsigned int u) {
    return float2{__uint_as_float(u << 16), __uint_as_float(u & 0xffff0000u)};
}

// ---------------------------------------------------------------------------
// Weight repack fp32 [M][Cin][3][3] -> bf16 [Mpad][Kpad], Kpad=(Cin/8)*96,
// k-order TAP-MAJOR: k = g*96 + tap*8 + cl, taps 9..11 zero, rows>=validM zero.
// ---------------------------------------------------------------------------
struct WSeg { const float* s; unsigned short* d; int K9; int Kpad; int validM; int n; };
struct WArgs { WSeg seg[9]; };

__global__ void wrepack_kernel(WArgs a)
{
    const WSeg sg = a.seg[blockIdx.y];
    int i = blockIdx.x * 256 + threadIdx.x;
    if (i >= sg.n) return;
    int co = i / sg.Kpad, r = i - co * sg.Kpad;
    int g = r / 96, q = r - g * 96;
    int tap = q >> 3, cl = q & 7;
    unsigned short v = 0;
    if (co < sg.validM && tap < 9)
        v = f2bf(sg.s[(size_t)co * sg.K9 + (g * 8 + cl) * 9 + tap]);
    sg.d[i] = v;
}

// ---------------------------------------------------------------------------
// Fused plain conv (N=64 tile, 2x32). SRCF 0: fp32 planar in; 1: NHWC8 bf16.
// Patch [4][34][8ch] bf16 in LDS; MFMA B-fragments read directly from patch.
// mode 0: NHWC8 bf16 out + leaky; mode 2: planar fp32 out, co<18, no leaky.
// ---------------------------------------------------------------------------
template <int MTW, int SRCF>
__global__ __launch_bounds__(256, 4) void fused_conv(
    const void* __restrict__ actv, const unsigned short* __restrict__ wpad,
    const float* __restrict__ bias, unsigned short* __restrict__ outb,
    float* __restrict__ outf, int Cin, int Cout, int mode)
{
    constexpr int SMB = 64 * 136 * 2;
    __shared__ char smem[SMB];
    unsigned short* patch = (unsigned short*)smem;   // [136 px][8ch]
    unsigned short* Es = (unsigned short*)smem;

    const int t = threadIdx.x;
    const int tile = blockIdx.x, b = blockIdx.z;
    const int lane = t & 63, wv = t >> 6, quad = lane >> 4, l15 = lane & 15;
    const int y0 = (tile >> 2) * 2, x0 = (tile & 3) * 32;
    const int Kpad = (Cin >> 3) * 96;
    const int ngrp = Cin >> 3;

    const int pr = t / 34, pc = t - 34 * pr;
    const int gy = y0 - 1 + pr, gx = x0 - 1 + pc;
    const bool pok = (t < 136) && gy >= 0 && gy < HW && gx >= 0 && gx < HW;
    const int gp = pok ? gy * HW + gx : 0;

    const float* actf = (const float*)actv;
    const unsigned short* acth = (const unsigned short*)actv;
    const size_t bofs = (size_t)b * Cin * HW2;

    int baddr[3][4];
#pragma unroll
    for (int st = 0; st < 3; ++st) {
        int tap = st * 4 + quad; tap = tap > 8 ? 8 : tap;
        int ky = (tap * 11) >> 5, kx = tap - 3 * ky;
#pragma unroll
        for (int nt = 0; nt < 4; ++nt) {
            int p = nt * 16 + l15, ly = p >> 5, lx = p & 31;
            baddr[st][nt] = ((ly + ky) * 34 + lx + kx) * 16;
        }
    }
    size_t aoff[MTW];
#pragma unroll
    for (int m = 0; m < MTW; ++m)
        aoff[m] = (size_t)((wv * MTW + m) * 16 + l15) * Kpad + quad * 8;

    f32x4 acc[MTW][4];
#pragma unroll
    for (int m = 0; m < MTW; ++m)
#pragma unroll
        for (int nt = 0; nt < 4; ++nt) acc[m][nt] = (f32x4)(0.f);

    auto load_grp = [&](int g) -> uint4 {
        uint4 u; u.x = u.y = u.z = u.w = 0;
        if (!pok) return u;
        if (SRCF == 1) {
            u = *(const uint4*)(acth + bofs + ((size_t)g * HW2 + gp) * 8);
        } else {
            const float* pl = actf + bofs + (size_t)(g * 8) * HW2 + gp;
            float v0 = pl[0], v1 = pl[HW2], v2 = pl[2 * HW2], v3 = pl[3 * HW2];
            float v4 = pl[4 * HW2], v5 = pl[5 * HW2], v6 = pl[6 * HW2], v7 = pl[7 * HW2];
            u.x = pk2(v0, v1); u.y = pk2(v2, v3);
            u.z = pk2(v4, v5); u.w = pk2(v6, v7);
        }
        return u;
    };

    uint4 cur = load_grp(0);
    for (int g = 0; g < ngrp; ++g) {
        if (t < 136) *(uint4*)(patch + t * 8) = cur;
        __syncthreads();
        uint4 nxt = cur;
        if (g + 1 < ngrp) nxt = load_grp(g + 1);

        const unsigned short* wg = wpad + g * 96;
#pragma unroll
        for (int st = 0; st < 3; ++st) {
            short8 bfr[4];
#pragma unroll
            for (int nt = 0; nt < 4; ++nt)
                bfr[nt] = *(const short8*)((char*)patch + baddr[st][nt]);
#pragma unroll
            for (int m = 0; m < MTW; ++m) {
                short8 a = *(const short8*)(wg + aoff[m] + st * 32);
#pragma unroll
                for (int nt = 0; nt < 4; ++nt)
                    acc[m][nt] = __builtin_amdgcn_mfma_f32_16x16x32_bf16(
                        a, bfr[nt], acc[m][nt], 0, 0, 0);
            }
        }
        __syncthreads();
        cur = nxt;
    }

    if (mode == 0) {
        constexpr int ESTR = 136;
#pragma unroll
        for (int m = 0; m < MTW; ++m) {
            int cb = (wv * MTW + m) * 16;
#pragma unroll
            for (int nt = 0; nt < 4; ++nt) {
                int px = nt * 16 + l15;
                int co = cb + quad * 4;
                unsigned int u0 = pk2(lrelu(acc[m][nt][0] + bias[co]),
                                      lrelu(acc[m][nt][1] + bias[co + 1]));
                unsigned int u1 = pk2(lrelu(acc[m][nt][2] + bias[co + 2]),
                                      lrelu(acc[m][nt][3] + bias[co + 3]));
                uint2 u; u.x = u0; u.y = u1;
                *(uint2*)&Es[px * ESTR + co] = u;
            }
        }
        __syncthreads();
        const int ng8 = Cout >> 3;
        unsigned short* ob = outb + (size_t)b * Cout * HW2;
        for (int tt = t; tt < 64 * ng8; tt += 256) {
            int cg = tt >> 6, px = tt & 63;
            int gp2 = (y0 + (px >> 5)) * HW + x0 + (px & 31);
            *(uint4*)(ob + ((size_t)cg * HW2 + gp2) * 8) =
                *(const uint4*)&Es[px * ESTR + cg * 8];
        }
    } else {
        float* of = outf + (size_t)b * 18 * HW2;
#pragma unroll
        for (int m = 0; m < MTW; ++m) {
            int cb = (wv * MTW + m) * 16;
#pragma unroll
            for (int nt = 0; nt < 4; ++nt) {
                int px = nt * 16 + l15;
                int gp2 = (y0 + (px >> 5)) * HW + x0 + (px & 31);
#pragma unroll
                for (int r = 0; r < 4; ++r) {
                    int co = cb + quad * 4 + r;
                    if (co < 18)
                        of[(size_t)co * HW2 + gp2] = acc[m][nt][r] + bias[co];
                }
            }
        }
    }
}

// ---------------------------------------------------------------------------
// Fused deformable conv, retiled to N=32 (2x16 px) for occupancy:
// grid 512 tiles x 4 batches = 2048 blocks (8/CU), LDS ~10.8 KB,
// __launch_bounds__(256,8) caps VGPR at 64 so 32 waves/CU fit.
// NHWC8 bf16 input; channel-vectorized bilinear (one task = 8 ch).
// mode 0: NHWC8 bf16 out + leaky; mode 1: planar fp32 out + leaky.
// ---------------------------------------------------------------------------
template <int MTW>
__global__ __launch_bounds__(256, 8) void fused_deform(
    const unsigned short* __restrict__ acth, const float* __restrict__ off,
    const unsigned short* __restrict__ wpad, const float* __restrict__ bias,
    unsigned short* __restrict__ outb, float* __restrict__ outf,
    int Cin, int Cout, int mode)
{
    constexpr int PATW = 26, PATP = 10 * PATW;           // 260 px (25 used/row)
    constexpr int CSTR = 104;
    constexpr int SMB1 = PATP * 16 + 32 * CSTR * 2;      // 4160 + 6656
    constexpr int SMB2 = 32 * 136 * 2;                   // Es 8704
    constexpr int SMB = SMB1 > SMB2 ? SMB1 : SMB2;
    __shared__ char smem[SMB];
    unsigned short* patch = (unsigned short*)smem;       // [260 px][8ch]
    unsigned short* Cs = (unsigned short*)(smem + PATP * 16);
    unsigned short* Es = (unsigned short*)smem;

    const int t = threadIdx.x;
    const int tile = blockIdx.x, b = blockIdx.z;
    const int lane = t & 63, wv = t >> 6, quad = lane >> 4, l15 = lane & 15;
    const int y0 = (tile >> 3) * 2, x0 = (tile & 7) * 16;
    const int Kpad = (Cin >> 3) * 96;
    const int ngrp = Cin >> 3;
    const int py0 = y0 - 4, px0 = x0 - 4;

    // zero Cs k-pad [72,96): 32 rows x 3 uint4
    if (t < 96) {
        int p = t / 3, j = t - 3 * p;
        uint4 z; z.x = z.y = z.z = z.w = 0;
        *(uint4*)&Cs[p * CSTR + 72 + j * 8] = z;
    }

    // ---- tap params: slots t (always, 288>256) and t+256 (t<32) ----
    int sp_[2], sk_[2], svalid[2];
    float swy[2], swx[2];
    int siy[2], six[2];
    int allin = 1;
    const float* offb = off + (size_t)b * 18 * HW2;
#pragma unroll
    for (int s = 0; s < 2; ++s) {
        int task = t + s * 256;
        svalid[s] = task < 288;
        int task2 = svalid[s] ? task : 0;
        int p = task2 / 9, k = task2 - 9 * p;
        sp_[s] = p; sk_[s] = k;
        int yy = y0 + (p >> 4), xx = x0 + (p & 15);
        float dy = offb[(2 * k) * HW2 + yy * HW + xx];
        float dx = offb[(2 * k + 1) * HW2 + yy * HW + xx];
        float py = (float)(yy + k / 3 - 1) + dy;
        float px = (float)(xx + k % 3 - 1) + dx;
        float fy = floorf(py), fx = floorf(px);
        swy[s] = py - fy; swx[s] = px - fx;
        int iy = (int)fy, ix = (int)fx;
        siy[s] = iy; six[s] = ix;
        bool ip = iy >= py0 && iy + 1 <= y0 + 5 && ix >= px0 && ix + 1 <= x0 + 20;
        if (!ip) allin = 0;
    }
    const int fast = __syncthreads_and(allin);

    // staging slots: i0 = t (<260), i1 = t+256 (t<4)
    const int r0 = t / PATW, c0_ = t - PATW * r0;
    const int gy0_ = py0 + r0, gx0_ = px0 + c0_;
    const bool ok0 = gy0_ >= 0 && gy0_ < HW && gx0_ >= 0 && gx0_ < HW;
    const int go0 = ok0 ? gy0_ * HW + gx0_ : 0;
    const int i1 = t + 256;
    const bool has1 = i1 < PATP;
    const int r1 = i1 / PATW, c1_ = i1 - PATW * r1;
    const int gy1_ = py0 + r1, gx1_ = px0 + c1_;
    const bool ok1 = has1 && gy1_ >= 0 && gy1_ < HW && gx1_ >= 0 && gx1_ < HW;
    const int go1 = ok1 ? gy1_ * HW + gx1_ : 0;

    const size_t bofs = (size_t)b * Cin * HW2;

    int baddr[3][2];
#pragma unroll
    for (int st = 0; st < 3; ++st)
#pragma unroll
        for (int nt = 0; nt < 2; ++nt)
            baddr[st][nt] = (nt * 16 + l15) * (CSTR * 2) + st * 64 + quad * 16;
    size_t aoff[MTW];
#pragma unroll
    for (int m = 0; m < MTW; ++m)
        aoff[m] = (size_t)((wv * MTW + m) * 16 + l15) * Kpad + quad * 8;

    f32x4 acc[MTW][2];
#pragma unroll
    for (int m = 0; m < MTW; ++m)
#pragma unroll
        for (int nt = 0; nt < 2; ++nt) acc[m][nt] = (f32x4)(0.f);

    float w00[2], w01[2], w10[2], w11[2];
    int pbase[2];
#pragma unroll
    for (int s = 0; s < 2; ++s) {
        float wy = swy[s], wx = swx[s];
        w00[s] = (1.f - wy) * (1.f - wx);
        w01[s] = (1.f - wy) * wx;
        w10[s] = wy * (1.f - wx);
        w11[s] = wy * wx;
        pbase[s] = ((siy[s] - py0) * PATW + (six[s] - px0)) * 16;  // bytes
    }

    auto load0 = [&](int g) -> uint4 {
        uint4 u; u.x = u.y = u.z = u.w = 0;
        if (ok0) u = *(const uint4*)(acth + bofs + ((size_t)g * HW2 + go0) * 8);
        return u;
    };
    auto load1 = [&](int g) -> uint4 {
        uint4 u; u.x = u.y = u.z = u.w = 0;
        if (ok1) u = *(const uint4*)(acth + bofs + ((size_t)g * HW2 + go1) * 8);
        return u;
    };

    uint4 cur0 = load0(0), cur1 = load1(0);
    for (int g = 0; g < ngrp; ++g) {
        *(uint4*)(patch + t * 8) = cur0;
        if (has1) *(uint4*)(patch + i1 * 8) = cur1;
        __syncthreads();
        uint4 nxt0 = cur0, nxt1 = cur1;
        if (g + 1 < ngrp) { nxt0 = load0(g + 1); nxt1 = load1(g + 1); }

        if (fast) {
#pragma unroll
            for (int s = 0; s < 2; ++s) {
                if (!svalid[s]) continue;
                const char* base = (const char*)patch + pbase[s];
                uint4 ca = *(const uint4*)base;
                uint4 cb_ = *(const uint4*)(base + 16);
                uint4 cc = *(const uint4*)(base + PATW * 16);
                uint4 cd = *(const uint4*)(base + PATW * 16 + 16);
                uint4 ou;
                {
                    float2 a = upk(ca.x), b2 = upk(cb_.x), c2 = upk(cc.x), d2 = upk(cd.x);
                    ou.x = pk2(w00[s] * a.x + w01[s] * b2.x + w10[s] * c2.x + w11[s] * d2.x,
                               w00[s] * a.y + w01[s] * b2.y + w10[s] * c2.y + w11[s] * d2.y);
                }
                {
                    float2 a = upk(ca.y), b2 = upk(cb_.y), c2 = upk(cc.y), d2 = upk(cd.y);
                    ou.y = pk2(w00[s] * a.x + w01[s] * b2.x + w10[s] * c2.x + w11[s] * d2.x,
                               w00[s] * a.y + w01[s] * b2.y + w10[s] * c2.y + w11[s] * d2.y);
                }
                {
                    float2 a = upk(ca.z), b2 = upk(cb_.z), c2 = upk(cc.z), d2 = upk(cd.z);
                    ou.z = pk2(w00[s] * a.x + w01[s] * b2.x + w10[s] * c2.x + w11[s] * d2.x,
                               w00[s] * a.y + w01[s] * b2.y + w10[s] * c2.y + w11[s] * d2.y);
                }
                {
                    float2 a = upk(ca.w), b2 = upk(cb_.w), c2 = upk(cc.w), d2 = upk(cd.w);
                    ou.w = pk2(w00[s] * a.x + w01[s] * b2.x + w10[s] * c2.x + w11[s] * d2.x,
                               w00[s] * a.y + w01[s] * b2.y + w10[s] * c2.y + w11[s] * d2.y);
                }
                *(uint4*)&Cs[sp_[s] * CSTR + sk_[s] * 8] = ou;
            }
        } else {
#pragma unroll
            for (int s = 0; s < 2; ++s) {
                if (!svalid[s]) continue;
                int iy = siy[s], ix = six[s], iy1 = iy + 1, ix1 = ix + 1;
                float vy0 = (iy >= 0 && iy < HW) ? 1.f : 0.f;
                float vy1 = (iy1 >= 0 && iy1 < HW) ? 1.f : 0.f;
                float vx0 = (ix >= 0 && ix < HW) ? 1.f : 0.f;
                float vx1 = (ix1 >= 0 && ix1 < HW) ? 1.f : 0.f;
                int cy0 = min(max(iy, 0), HW - 1), cy1 = min(max(iy1, 0), HW - 1);
                int cx0 = min(max(ix, 0), HW - 1), cx1 = min(max(ix1, 0), HW - 1);
                float m00 = w00[s] * vy0 * vx0, m01 = w01[s] * vy0 * vx1;
                float m10 = w10[s] * vy1 * vx0, m11 = w11[s] * vy1 * vx1;
                const unsigned short* gb = acth + bofs + (size_t)g * HW2 * 8;
                uint4 ca = *(const uint4*)(gb + (size_t)(cy0 * HW + cx0) * 8);
                uint4 cb_ = *(const uint4*)(gb + (size_t)(cy0 * HW + cx1) * 8);
                uint4 cc = *(const uint4*)(gb + (size_t)(cy1 * HW + cx0) * 8);
                uint4 cd = *(const uint4*)(gb + (size_t)(cy1 * HW + cx1) * 8);
                uint4 ou;
                {
                    float2 a = upk(ca.x), b2 = upk(cb_.x), c2 = upk(cc.x), d2 = upk(cd.x);
                    ou.x = pk2(m00 * a.x + m01 * b2.x + m10 * c2.x + m11 * d2.x,
                               m00 * a.y + m01 * b2.y + m10 * c2.y + m11 * d2.y);
                }
                {
                    float2 a = upk(ca.y), b2 = upk(cb_.y), c2 = upk(cc.y), d2 = upk(cd.y);
                    ou.y = pk2(m00 * a.x + m01 * b2.x + m10 * c2.x + m11 * d2.x,
                               m00 * a.y + m01 * b2.y + m10 * c2.y + m11 * d2.y);
                }
                {
                    float2 a = upk(ca.z), b2 = upk(cb_.z), c2 = upk(cc.z), d2 = upk(cd.z);
                    ou.z = pk2(m00 * a.x + m01 * b2.x + m10 * c2.x + m11 * d2.x,
                               m00 * a.y + m01 * b2.y + m10 * c2.y + m11 * d2.y);
                }
                {
                    float2 a = upk(ca.w), b2 = upk(cb_.w), c2 = upk(cc.w), d2 = upk(cd.w);
                    ou.w = pk2(m00 * a.x + m01 * b2.x + m10 * c2.x + m11 * d2.x,
                               m00 * a.y + m01 * b2.y + m10 * c2.y + m11 * d2.y);
                }
                *(uint4*)&Cs[sp_[s] * CSTR + sk_[s] * 8] = ou;
            }
        }
        __syncthreads();

        const unsigned short* wg = wpad + g * 96;
#pragma unroll
        for (int st = 0; st < 3; ++st) {
            short8 bfr[2];
#pragma unroll
            for (int nt = 0; nt < 2; ++nt)
                bfr[nt] = *(const short8*)((char*)Cs + baddr[st][nt]);
#pragma unroll
            for (int m = 0; m < MTW; ++m) {
                short8 a = *(const short8*)(wg + aoff[m] + st * 32);
#pragma unroll
                for (int nt = 0; nt < 2; ++nt)
                    acc[m][nt] = __builtin_amdgcn_mfma_f32_16x16x32_bf16(
                        a, bfr[nt], acc[m][nt], 0, 0, 0);
            }
        }
        __syncthreads();
        cur0 = nxt0; cur1 = nxt1;
    }

    if (mode == 0) {
        constexpr int ESTR = 136;
#pragma unroll
        for (int m = 0; m < MTW; ++m) {
            int cb = (wv * MTW + m) * 16;
#pragma unroll
            for (int nt = 0; nt < 2; ++nt) {
                int px = nt * 16 + l15;
                int co = cb + quad * 4;
                unsigned int u0 = pk2(lrelu(acc[m][nt][0] + bias[co]),
                                      lrelu(acc[m][nt][1] + bias[co + 1]));
                unsigned int u1 = pk2(lrelu(acc[m][nt][2] + bias[co + 2]),
                                      lrelu(acc[m][nt][3] + bias[co + 3]));
                uint2 u; u.x = u0; u.y = u1;
                *(uint2*)&Es[px * ESTR + co] = u;
            }
        }
        __syncthreads();
        const int ng8 = Cout >> 3;
        unsigned short* ob = outb + (size_t)b * Cout * HW2;
        for (int tt = t; tt < 32 * ng8; tt += 256) {
            int cg = tt >> 5, px = tt & 31;
            int gp2 = (y0 + (px >> 4)) * HW + x0 + (px & 15);
            *(uint4*)(ob + ((size_t)cg * HW2 + gp2) * 8) =
                *(const uint4*)&Es[px * ESTR + cg * 8];
        }
    } else {
        float* of = outf + (size_t)b * Cout * HW2;
#pragma unroll
        for (int m = 0; m < MTW; ++m) {
            int cb = (wv * MTW + m) * 16;
#pragma unroll
            for (int nt = 0; nt < 2; ++nt) {
                int px = nt * 16 + l15;
                int gp2 = (y0 + (px >> 4)) * HW + x0 + (px & 15);
#pragma unroll
                for (int r = 0; r < 4; ++r) {
                    int co = cb + quad * 4 + r;
                    of[(size_t)co * HW2 + gp2] = lrelu(acc[m][nt][r] + bias[co]);
                }
            }
        }
    }
}

// ---------------------------------------------------------------------------
extern "C" void kernel_launch(void* const* d_in, const int* in_sizes, int n_in,
                              void* d_out, int out_size, void* d_ws,
                              size_t ws_size, hipStream_t stream)
{
    const float* x = (const float*)d_in[0];
    const float* p[18];
    for (int i = 0; i < 18; ++i) p[i] = (const float*)d_in[1 + i];

    char* ws = (char*)d_ws;
    unsigned short* A1 = (unsigned short*)ws;              // NHWC8 bf16
    unsigned short* A2 = (unsigned short*)(ws + 16777216);
    float* OFF = (float*)(ws + 33554432);                  // fp32 planar 18ch
    unsigned short* WB = (unsigned short*)(ws + 38273024);

    unsigned short* Wc1 = WB;             // 128 x 768
    unsigned short* Wo1 = Wc1 + 98304;    // 64  x 1536 (18 valid)
    unsigned short* Wd1 = Wo1 + 98304;    // 128 x 1536
    unsigned short* Wc2 = Wd1 + 196608;   // 128 x 1536
    unsigned short* Wo2 = Wc2 + 196608;   // 64  x 1536 (18 valid)
    unsigned short* Wd2 = Wo2 + 98304;    // 128 x 1536
    unsigned short* Wc3 = Wd2 + 196608;   // 64  x 1536
    unsigned short* Wo3 = Wc3 + 98304;    // 64  x 768  (18 valid)
    unsigned short* Wd3 = Wo3 + 49152;    // 64  x 768

    WArgs wa;
    wa.seg[0] = {p[0],  Wc1,  576,  768, 128,  98304};
    wa.seg[1] = {p[2],  Wo1, 1152, 1536,  18,  98304};
    wa.seg[2] = {p[4],  Wd1, 1152, 1536, 128, 196608};
    wa.seg[3] = {p[6],  Wc2, 1152, 1536, 128, 196608};
    wa.seg[4] = {p[8],  Wo2, 1152, 1536,  18,  98304};
    wa.seg[5] = {p[10], Wd2, 1152, 1536, 128, 196608};
    wa.seg[6] = {p[12], Wc3, 1152, 1536,  64,  98304};
    wa.seg[7] = {p[14], Wo3,  576,  768,  18,  49152};
    wa.seg[8] = {p[16], Wd3,  576,  768,  64,  49152};
    wrepack_kernel<<<dim3(768, 9), 256, 0, stream>>>(wa);

    dim3 g(256, 1, 4);      // conv grid: 2x32 tiles
    dim3 gd(512, 1, 4);     // deform grid: 2x16 tiles
    // stage 1
    fused_conv<2, 0><<<g, 256, 0, stream>>>(x, Wc1, p[1], A1, nullptr, 64, 128, 0);
    fused_conv<1, 1><<<g, 256, 0, stream>>>(A1, Wo1, p[3], nullptr, OFF, 128, 64, 2);
    fused_deform<2><<<gd, 256, 0, stream>>>(A1, OFF, Wd1, p[5], A2, nullptr, 128, 128, 0);
    // stage 2
    fused_conv<2, 1><<<g, 256, 0, stream>>>(A2, Wc2, p[7], A1, nullptr, 128, 128, 0);
    fused_conv<1, 1><<<g, 256, 0, stream>>>(A1, Wo2, p[9], nullptr, OFF, 128, 64, 2);
    fused_deform<2><<<gd, 256, 0, stream>>>(A1, OFF, Wd2, p[11], A2, nullptr, 128, 128, 0);
    // stage 3
    fused_conv<1, 1><<<g, 256, 0, stream>>>(A2, Wc3, p[13], A1, nullptr, 128, 64, 0);
    fused_conv<1, 1><<<g, 256, 0, stream>>>(A1, Wo3, p[15], nullptr, OFF, 64, 64, 2);
    fused_deform<1><<<gd, 256, 0, stream>>>(A1, OFF, Wd3, p[17], nullptr, (float*)d_out, 64, 64, 1);
}

// Round 8
// 505.726 us; speedup vs baseline: 1.7522x; 1.7522x over previous
//
#include <hip/hip_runtime.h>
#include <hip/hip_bf16.h>

#define HW 128
#define HW2 16384
#define NEG 0.2f

typedef __attribute__((ext_vector_type(8))) short short8;
typedef __attribute__((ext_vector_type(4))) float f32x4;

__device__ __forceinline__ float lrelu(float v) { return v >= 0.f ? v : NEG * v; }
__device__ __forceinline__ unsigned short f2bf(float f) {
    unsigned int u = __float_as_uint(f);
    u = (u + 0x7fffu + ((u >> 16) & 1u)) >> 16;
    return (unsigned short)u;
}
__device__ __forceinline__ unsigned int pk2(float a, float b) {
    __hip_bfloat162 h = __float22bfloat162_rn(float2{a, b});
    return *(unsigned int*)&h;
}
__device__ __forceinline__ float2 upk(unsigned int u) {
    return float2{__uint_as_float(u << 16), __uint_as_float(u & 0xffff0000u)};
}

// ---------------------------------------------------------------------------
// Weight repack fp32 [M][Cin][3][3] -> bf16 [Mpad][Kpad], Kpad=(Cin/8)*96,
// k-order TAP-MAJOR: k = g*96 + tap*8 + cl, taps 9..11 zero, rows>=validM zero.
// ---------------------------------------------------------------------------
struct WSeg { const float* s; unsigned short* d; int K9; int Kpad; int validM; int n; };
struct WArgs { WSeg seg[9]; };

__global__ void wrepack_kernel(WArgs a)
{
    const WSeg sg = a.seg[blockIdx.y];
    int i = blockIdx.x * 256 + threadIdx.x;
    if (i >= sg.n) return;
    int co = i / sg.Kpad, r = i - co * sg.Kpad;
    int g = r / 96, q = r - g * 96;
    int tap = q >> 3, cl = q & 7;
    unsigned short v = 0;
    if (co < sg.validM && tap < 9)
        v = f2bf(sg.s[(size_t)co * sg.K9 + (g * 8 + cl) * 9 + tap]);
    sg.d[i] = v;
}

// ---------------------------------------------------------------------------
// Fused plain conv (N=64 tile, 2x32) — unchanged from R6 (proven).
// ---------------------------------------------------------------------------
template <int MTW, int SRCF>
__global__ __launch_bounds__(256, 4) void fused_conv(
    const void* __restrict__ actv, const unsigned short* __restrict__ wpad,
    const float* __restrict__ bias, unsigned short* __restrict__ outb,
    float* __restrict__ outf, int Cin, int Cout, int mode)
{
    constexpr int SMB = 64 * 136 * 2;
    __shared__ char smem[SMB];
    unsigned short* patch = (unsigned short*)smem;   // [136 px][8ch]
    unsigned short* Es = (unsigned short*)smem;

    const int t = threadIdx.x;
    const int tile = blockIdx.x, b = blockIdx.z;
    const int lane = t & 63, wv = t >> 6, quad = lane >> 4, l15 = lane & 15;
    const int y0 = (tile >> 2) * 2, x0 = (tile & 3) * 32;
    const int Kpad = (Cin >> 3) * 96;
    const int ngrp = Cin >> 3;

    const int pr = t / 34, pc = t - 34 * pr;
    const int gy = y0 - 1 + pr, gx = x0 - 1 + pc;
    const bool pok = (t < 136) && gy >= 0 && gy < HW && gx >= 0 && gx < HW;
    const int gp = pok ? gy * HW + gx : 0;

    const float* actf = (const float*)actv;
    const unsigned short* acth = (const unsigned short*)actv;
    const size_t bofs = (size_t)b * Cin * HW2;

    int baddr[3][4];
#pragma unroll
    for (int st = 0; st < 3; ++st) {
        int tap = st * 4 + quad; tap = tap > 8 ? 8 : tap;
        int ky = (tap * 11) >> 5, kx = tap - 3 * ky;
#pragma unroll
        for (int nt = 0; nt < 4; ++nt) {
            int p = nt * 16 + l15, ly = p >> 5, lx = p & 31;
            baddr[st][nt] = ((ly + ky) * 34 + lx + kx) * 16;
        }
    }
    size_t aoff[MTW];
#pragma unroll
    for (int m = 0; m < MTW; ++m)
        aoff[m] = (size_t)((wv * MTW + m) * 16 + l15) * Kpad + quad * 8;

    f32x4 acc[MTW][4];
#pragma unroll
    for (int m = 0; m < MTW; ++m)
#pragma unroll
        for (int nt = 0; nt < 4; ++nt) acc[m][nt] = (f32x4)(0.f);

    auto load_grp = [&](int g) -> uint4 {
        uint4 u; u.x = u.y = u.z = u.w = 0;
        if (!pok) return u;
        if (SRCF == 1) {
            u = *(const uint4*)(acth + bofs + ((size_t)g * HW2 + gp) * 8);
        } else {
            const float* pl = actf + bofs + (size_t)(g * 8) * HW2 + gp;
            float v0 = pl[0], v1 = pl[HW2], v2 = pl[2 * HW2], v3 = pl[3 * HW2];
            float v4 = pl[4 * HW2], v5 = pl[5 * HW2], v6 = pl[6 * HW2], v7 = pl[7 * HW2];
            u.x = pk2(v0, v1); u.y = pk2(v2, v3);
            u.z = pk2(v4, v5); u.w = pk2(v6, v7);
        }
        return u;
    };

    uint4 cur = load_grp(0);
    for (int g = 0; g < ngrp; ++g) {
        if (t < 136) *(uint4*)(patch + t * 8) = cur;
        __syncthreads();
        uint4 nxt = cur;
        if (g + 1 < ngrp) nxt = load_grp(g + 1);

        const unsigned short* wg = wpad + g * 96;
#pragma unroll
        for (int st = 0; st < 3; ++st) {
            short8 bfr[4];
#pragma unroll
            for (int nt = 0; nt < 4; ++nt)
                bfr[nt] = *(const short8*)((char*)patch + baddr[st][nt]);
#pragma unroll
            for (int m = 0; m < MTW; ++m) {
                short8 a = *(const short8*)(wg + aoff[m] + st * 32);
#pragma unroll
                for (int nt = 0; nt < 4; ++nt)
                    acc[m][nt] = __builtin_amdgcn_mfma_f32_16x16x32_bf16(
                        a, bfr[nt], acc[m][nt], 0, 0, 0);
            }
        }
        __syncthreads();
        cur = nxt;
    }

    if (mode == 0) {
        constexpr int ESTR = 136;
#pragma unroll
        for (int m = 0; m < MTW; ++m) {
            int cb = (wv * MTW + m) * 16;
#pragma unroll
            for (int nt = 0; nt < 4; ++nt) {
                int px = nt * 16 + l15;
                int co = cb + quad * 4;
                unsigned int u0 = pk2(lrelu(acc[m][nt][0] + bias[co]),
                                      lrelu(acc[m][nt][1] + bias[co + 1]));
                unsigned int u1 = pk2(lrelu(acc[m][nt][2] + bias[co + 2]),
                                      lrelu(acc[m][nt][3] + bias[co + 3]));
                uint2 u; u.x = u0; u.y = u1;
                *(uint2*)&Es[px * ESTR + co] = u;
            }
        }
        __syncthreads();
        const int ng8 = Cout >> 3;
        unsigned short* ob = outb + (size_t)b * Cout * HW2;
        for (int tt = t; tt < 64 * ng8; tt += 256) {
            int cg = tt >> 6, px = tt & 63;
            int gp2 = (y0 + (px >> 5)) * HW + x0 + (px & 31);
            *(uint4*)(ob + ((size_t)cg * HW2 + gp2) * 8) =
                *(const uint4*)&Es[px * ESTR + cg * 8];
        }
    } else {
        float* of = outf + (size_t)b * 18 * HW2;
#pragma unroll
        for (int m = 0; m < MTW; ++m) {
            int cb = (wv * MTW + m) * 16;
#pragma unroll
            for (int nt = 0; nt < 4; ++nt) {
                int px = nt * 16 + l15;
                int gp2 = (y0 + (px >> 5)) * HW + x0 + (px & 31);
#pragma unroll
                for (int r = 0; r < 4; ++r) {
                    int co = cb + quad * 4 + r;
                    if (co < 18)
                        of[(size_t)co * HW2 + gp2] = acc[m][nt][r] + bias[co];
                }
            }
        }
    }
}

// ---------------------------------------------------------------------------
// Fused deformable conv, N=32 (2x16 px), 2048 blocks, REGISTER-DISCIPLINED
// to fit 64 VGPR (8 blocks/CU): LDS double-buffered patch (no reg prefetch),
// minimal persistent tap state, sequential corner accumulation. Slow path
// (out-of-patch samples, ~never) recomputes per group, register-light.
// mode 0: NHWC8 bf16 out + leaky; mode 1: planar fp32 out + leaky.
// ---------------------------------------------------------------------------
template <int MTW>
__global__ __launch_bounds__(256, 8) void fused_deform(
    const unsigned short* __restrict__ acth, const float* __restrict__ off,
    const unsigned short* __restrict__ wpad, const float* __restrict__ bias,
    unsigned short* __restrict__ outb, float* __restrict__ outf,
    int Cin, int Cout, int mode)
{
    constexpr int PATW = 26, PATP = 10 * PATW;           // 260 px slots
    constexpr int CSTR = 104;
    constexpr int SMB1 = 2 * PATP * 16 + 32 * CSTR * 2;  // 8320 + 6656 = 14976
    constexpr int SMB2 = 32 * 136 * 2;                   // Es 8704
    constexpr int SMB = SMB1 > SMB2 ? SMB1 : SMB2;
    __shared__ char smem[SMB];
    unsigned short* patch0 = (unsigned short*)smem;              // [260][8]
    unsigned short* patch1 = (unsigned short*)(smem + PATP * 16);
    unsigned short* Cs = (unsigned short*)(smem + 2 * PATP * 16);
    unsigned short* Es = (unsigned short*)smem;

    const int t = threadIdx.x;
    const int tile = blockIdx.x, b = blockIdx.z;
    const int lane = t & 63, wv = t >> 6, quad = lane >> 4, l15 = lane & 15;
    const int y0 = (tile >> 3) * 2, x0 = (tile & 7) * 16;
    const int Kpad = (Cin >> 3) * 96;
    const int ngrp = Cin >> 3;
    const int py0 = y0 - 4, px0 = x0 - 4;

    // zero Cs k-pad [72,96): 32 rows x 3 uint4
    if (t < 96) {
        int p = t / 3, j = t - 3 * p;
        uint4 z; z.x = z.y = z.z = z.w = 0;
        *(uint4*)&Cs[p * CSTR + 72 + j * 8] = z;
    }

    // ---- phase 0: fast-path tap params only (slots t, t+256) ----
    float w00[2], w01[2], w10[2], w11[2];
    int pbase[2], csad[2], svalid[2];
    int allin = 1;
    {
        const float* offb = off + (size_t)b * 18 * HW2;
#pragma unroll
        for (int s = 0; s < 2; ++s) {
            int task = t + s * 256;
            svalid[s] = task < 288;
            int task2 = svalid[s] ? task : 0;
            int p = task2 / 9, k = task2 - 9 * p;
            int yy = y0 + (p >> 4), xx = x0 + (p & 15);
            float dy = offb[(2 * k) * HW2 + yy * HW + xx];
            float dx = offb[(2 * k + 1) * HW2 + yy * HW + xx];
            float py = (float)(yy + k / 3 - 1) + dy;
            float px = (float)(xx + k % 3 - 1) + dx;
            float fy = floorf(py), fx = floorf(px);
            float wy = py - fy, wx = px - fx;
            int iy = (int)fy, ix = (int)fx;
            w00[s] = (1.f - wy) * (1.f - wx);
            w01[s] = (1.f - wy) * wx;
            w10[s] = wy * (1.f - wx);
            w11[s] = wy * wx;
            pbase[s] = ((iy - py0) * PATW + (ix - px0)) * 16;     // bytes
            csad[s] = (p * CSTR + k * 8) * 2;                     // bytes
            bool ip = iy >= py0 && iy + 1 <= y0 + 5 && ix >= px0 && ix + 1 <= x0 + 20;
            if (!ip) allin = 0;
        }
    }
    const int fast = __syncthreads_and(allin);

    // staging geometry (slot0 = t < 260 always; slot1 = t+256, t < 4)
    const int r0 = t / PATW, c0_ = t - PATW * r0;
    const int gy0_ = py0 + r0, gx0_ = px0 + c0_;
    const bool ok0 = gy0_ >= 0 && gy0_ < HW && gx0_ >= 0 && gx0_ < HW;
    const int go0 = ok0 ? gy0_ * HW + gx0_ : 0;
    const bool has1 = t < PATP - 256;
    const int i1 = t + 256;
    const int r1 = i1 / PATW, c1_ = i1 - PATW * r1;
    const int gy1_ = py0 + r1, gx1_ = px0 + c1_;
    const bool ok1 = has1 && gy1_ >= 0 && gy1_ < HW && gx1_ >= 0 && gx1_ < HW;
    const int go1 = ok1 ? gy1_ * HW + gx1_ : 0;

    const size_t bofs = (size_t)b * Cin * HW2;

    size_t aoff[MTW];
#pragma unroll
    for (int m = 0; m < MTW; ++m)
        aoff[m] = (size_t)((wv * MTW + m) * 16 + l15) * Kpad + quad * 8;
    const int bb0 = l15 * (CSTR * 2) + quad * 16;        // B-frag base (bytes)
    const int bb1 = bb0 + 16 * (CSTR * 2);

    f32x4 acc[MTW][2];
#pragma unroll
    for (int m = 0; m < MTW; ++m)
#pragma unroll
        for (int nt = 0; nt < 2; ++nt) acc[m][nt] = (f32x4)(0.f);

    if (fast) {
        // preload group 0 into patch0
        {
            uint4 u; u.x = u.y = u.z = u.w = 0;
            if (ok0) u = *(const uint4*)(acth + bofs + (size_t)go0 * 8);
            *(uint4*)(patch0 + t * 8) = u;
            uint4 v; v.x = v.y = v.z = v.w = 0;
            if (ok1) v = *(const uint4*)(acth + bofs + (size_t)go1 * 8);
            if (has1) *(uint4*)(patch1 - PATP * 8 + i1 * 8) = v;  // still patch0 region
        }
        __syncthreads();

        for (int g = 0; g < ngrp; ++g) {
            unsigned short* pb = (g & 1) ? patch1 : patch0;
            unsigned short* pn = (g & 1) ? patch0 : patch1;

            // col build: sequential corner accumulation (low live-reg count)
#pragma unroll
            for (int s = 0; s < 2; ++s) {
                if (!svalid[s]) continue;
                const char* base = (const char*)pb + pbase[s];
                float f0, f1, f2, f3, f4, f5, f6, f7;
                {
                    uint4 c = *(const uint4*)base;
                    float2 p0 = upk(c.x), p1 = upk(c.y), p2 = upk(c.z), p3 = upk(c.w);
                    float w = w00[s];
                    f0 = w * p0.x; f1 = w * p0.y; f2 = w * p1.x; f3 = w * p1.y;
                    f4 = w * p2.x; f5 = w * p2.y; f6 = w * p3.x; f7 = w * p3.y;
                }
                {
                    uint4 c = *(const uint4*)(base + 16);
                    float2 p0 = upk(c.x), p1 = upk(c.y), p2 = upk(c.z), p3 = upk(c.w);
                    float w = w01[s];
                    f0 += w * p0.x; f1 += w * p0.y; f2 += w * p1.x; f3 += w * p1.y;
                    f4 += w * p2.x; f5 += w * p2.y; f6 += w * p3.x; f7 += w * p3.y;
                }
                {
                    uint4 c = *(const uint4*)(base + PATW * 16);
                    float2 p0 = upk(c.x), p1 = upk(c.y), p2 = upk(c.z), p3 = upk(c.w);
                    float w = w10[s];
                    f0 += w * p0.x; f1 += w * p0.y; f2 += w * p1.x; f3 += w * p1.y;
                    f4 += w * p2.x; f5 += w * p2.y; f6 += w * p3.x; f7 += w * p3.y;
                }
                {
                    uint4 c = *(const uint4*)(base + PATW * 16 + 16);
                    float2 p0 = upk(c.x), p1 = upk(c.y), p2 = upk(c.z), p3 = upk(c.w);
                    float w = w11[s];
                    f0 += w * p0.x; f1 += w * p0.y; f2 += w * p1.x; f3 += w * p1.y;
                    f4 += w * p2.x; f5 += w * p2.y; f6 += w * p3.x; f7 += w * p3.y;
                }
                uint4 ou;
                ou.x = pk2(f0, f1); ou.y = pk2(f2, f3);
                ou.z = pk2(f4, f5); ou.w = pk2(f6, f7);
                *(uint4*)((char*)Cs + csad[s]) = ou;
            }

            // stage group g+1 into the other patch buffer
            if (g + 1 < ngrp) {
                const unsigned short* gb = acth + bofs + (size_t)(g + 1) * HW2 * 8;
                uint4 u; u.x = u.y = u.z = u.w = 0;
                if (ok0) u = *(const uint4*)(gb + (size_t)go0 * 8);
                *(uint4*)(pn + t * 8) = u;
                uint4 v; v.x = v.y = v.z = v.w = 0;
                if (ok1) v = *(const uint4*)(gb + (size_t)go1 * 8);
                if (has1) *(uint4*)(pn + i1 * 8) = v;
            }
            __syncthreads();

            const unsigned short* wg = wpad + g * 96;
#pragma unroll
            for (int st = 0; st < 3; ++st) {
                short8 b0 = *(const short8*)((char*)Cs + bb0 + st * 64);
                short8 b1 = *(const short8*)((char*)Cs + bb1 + st * 64);
#pragma unroll
                for (int m = 0; m < MTW; ++m) {
                    short8 a = *(const short8*)(wg + aoff[m] + st * 32);
                    acc[m][0] = __builtin_amdgcn_mfma_f32_16x16x32_bf16(a, b0, acc[m][0], 0, 0, 0);
                    acc[m][1] = __builtin_amdgcn_mfma_f32_16x16x32_bf16(a, b1, acc[m][1], 0, 0, 0);
                }
            }
            __syncthreads();
        }
    } else {
        // slow path: recompute taps per group from offsets; global corner reads.
        const float* offb = off + (size_t)b * 18 * HW2;
        for (int g = 0; g < ngrp; ++g) {
            const unsigned short* gb = acth + bofs + (size_t)g * HW2 * 8;
#pragma unroll
            for (int s = 0; s < 2; ++s) {
                if (!svalid[s]) continue;
                int task = t + s * 256;
                int p = task / 9, k = task - 9 * p;
                int yy = y0 + (p >> 4), xx = x0 + (p & 15);
                float dy = offb[(2 * k) * HW2 + yy * HW + xx];
                float dx = offb[(2 * k + 1) * HW2 + yy * HW + xx];
                float py = (float)(yy + k / 3 - 1) + dy;
                float px = (float)(xx + k % 3 - 1) + dx;
                float fy = floorf(py), fx = floorf(px);
                float wy = py - fy, wx = px - fx;
                int iy = (int)fy, ix = (int)fx;
                float f0 = 0, f1 = 0, f2 = 0, f3 = 0, f4 = 0, f5 = 0, f6 = 0, f7 = 0;
#pragma unroll
                for (int q = 0; q < 4; ++q) {
                    int ddy = q >> 1, ddx = q & 1;
                    int sy = iy + ddy, sx = ix + ddx;
                    float w = (ddy ? wy : 1.f - wy) * (ddx ? wx : 1.f - wx);
                    if (sy < 0 || sy >= HW || sx < 0 || sx >= HW) w = 0.f;
                    int cy = min(max(sy, 0), HW - 1), cx = min(max(sx, 0), HW - 1);
                    uint4 c = *(const uint4*)(gb + (size_t)(cy * HW + cx) * 8);
                    float2 p0 = upk(c.x), p1 = upk(c.y), p2 = upk(c.z), p3 = upk(c.w);
                    f0 += w * p0.x; f1 += w * p0.y; f2 += w * p1.x; f3 += w * p1.y;
                    f4 += w * p2.x; f5 += w * p2.y; f6 += w * p3.x; f7 += w * p3.y;
                }
                uint4 ou;
                ou.x = pk2(f0, f1); ou.y = pk2(f2, f3);
                ou.z = pk2(f4, f5); ou.w = pk2(f6, f7);
                *(uint4*)((char*)Cs + csad[s]) = ou;
            }
            __syncthreads();

            const unsigned short* wg = wpad + g * 96;
#pragma unroll
            for (int st = 0; st < 3; ++st) {
                short8 b0 = *(const short8*)((char*)Cs + bb0 + st * 64);
                short8 b1 = *(const short8*)((char*)Cs + bb1 + st * 64);
#pragma unroll
                for (int m = 0; m < MTW; ++m) {
                    short8 a = *(const short8*)(wg + aoff[m] + st * 32);
                    acc[m][0] = __builtin_amdgcn_mfma_f32_16x16x32_bf16(a, b0, acc[m][0], 0, 0, 0);
                    acc[m][1] = __builtin_amdgcn_mfma_f32_16x16x32_bf16(a, b1, acc[m][1], 0, 0, 0);
                }
            }
            __syncthreads();
        }
    }

    // ---- epilogue ----
    if (mode == 0) {
        constexpr int ESTR = 136;
#pragma unroll
        for (int m = 0; m < MTW; ++m) {
            int cb = (wv * MTW + m) * 16;
#pragma unroll
            for (int nt = 0; nt < 2; ++nt) {
                int px = nt * 16 + l15;
                int co = cb + quad * 4;
                unsigned int u0 = pk2(lrelu(acc[m][nt][0] + bias[co]),
                                      lrelu(acc[m][nt][1] + bias[co + 1]));
                unsigned int u1 = pk2(lrelu(acc[m][nt][2] + bias[co + 2]),
                                      lrelu(acc[m][nt][3] + bias[co + 3]));
                uint2 u; u.x = u0; u.y = u1;
                *(uint2*)&Es[px * ESTR + co] = u;
            }
        }
        __syncthreads();
        const int ng8 = Cout >> 3;
        unsigned short* ob = outb + (size_t)b * Cout * HW2;
        for (int tt = t; tt < 32 * ng8; tt += 256) {
            int cg = tt >> 5, px = tt & 31;
            int gp2 = (y0 + (px >> 4)) * HW + x0 + (px & 15);
            *(uint4*)(ob + ((size_t)cg * HW2 + gp2) * 8) =
                *(const uint4*)&Es[px * ESTR + cg * 8];
        }
    } else {
        float* of = outf + (size_t)b * Cout * HW2;
#pragma unroll
        for (int m = 0; m < MTW; ++m) {
            int cb = (wv * MTW + m) * 16;
#pragma unroll
            for (int nt = 0; nt < 2; ++nt) {
                int px = nt * 16 + l15;
                int gp2 = (y0 + (px >> 4)) * HW + x0 + (px & 15);
#pragma unroll
                for (int r = 0; r < 4; ++r) {
                    int co = cb + quad * 4 + r;
                    of[(size_t)co * HW2 + gp2] = lrelu(acc[m][nt][r] + bias[co]);
                }
            }
        }
    }
}

// ---------------------------------------------------------------------------
extern "C" void kernel_launch(void* const* d_in, const int* in_sizes, int n_in,
                              void* d_out, int out_size, void* d_ws,
                              size_t ws_size, hipStream_t stream)
{
    const float* x = (const float*)d_in[0];
    const float* p[18];
    for (int i = 0; i < 18; ++i) p[i] = (const float*)d_in[1 + i];

    char* ws = (char*)d_ws;
    unsigned short* A1 = (unsigned short*)ws;              // NHWC8 bf16
    unsigned short* A2 = (unsigned short*)(ws + 16777216);
    float* OFF = (float*)(ws + 33554432);                  // fp32 planar 18ch
    unsigned short* WB = (unsigned short*)(ws + 38273024);

    unsigned short* Wc1 = WB;             // 128 x 768
    unsigned short* Wo1 = Wc1 + 98304;    // 64  x 1536 (18 valid)
    unsigned short* Wd1 = Wo1 + 98304;    // 128 x 1536
    unsigned short* Wc2 = Wd1 + 196608;   // 128 x 1536
    unsigned short* Wo2 = Wc2 + 196608;   // 64  x 1536 (18 valid)
    unsigned short* Wd2 = Wo2 + 98304;    // 128 x 1536
    unsigned short* Wc3 = Wd2 + 196608;   // 64  x 1536
    unsigned short* Wo3 = Wc3 + 98304;    // 64  x 768  (18 valid)
    unsigned short* Wd3 = Wo3 + 49152;    // 64  x 768

    WArgs wa;
    wa.seg[0] = {p[0],  Wc1,  576,  768, 128,  98304};
    wa.seg[1] = {p[2],  Wo1, 1152, 1536,  18,  98304};
    wa.seg[2] = {p[4],  Wd1, 1152, 1536, 128, 196608};
    wa.seg[3] = {p[6],  Wc2, 1152, 1536, 128, 196608};
    wa.seg[4] = {p[8],  Wo2, 1152, 1536,  18,  98304};
    wa.seg[5] = {p[10], Wd2, 1152, 1536, 128, 196608};
    wa.seg[6] = {p[12], Wc3, 1152, 1536,  64,  98304};
    wa.seg[7] = {p[14], Wo3,  576,  768,  18,  49152};
    wa.seg[8] = {p[16], Wd3,  576,  768,  64,  49152};
    wrepack_kernel<<<dim3(768, 9), 256, 0, stream>>>(wa);

    dim3 g(256, 1, 4);      // conv grid: 2x32 tiles
    dim3 gd(512, 1, 4);     // deform grid: 2x16 tiles
    // stage 1
    fused_conv<2, 0><<<g, 256, 0, stream>>>(x, Wc1, p[1], A1, nullptr, 64, 128, 0);
    fused_conv<1, 1><<<g, 256, 0, stream>>>(A1, Wo1, p[3], nullptr, OFF, 128, 64, 2);
    fused_deform<2><<<gd, 256, 0, stream>>>(A1, OFF, Wd1, p[5], A2, nullptr, 128, 128, 0);
    // stage 2
    fused_conv<2, 1><<<g, 256, 0, stream>>>(A2, Wc2, p[7], A1, nullptr, 128, 128, 0);
    fused_conv<1, 1><<<g, 256, 0, stream>>>(A1, Wo2, p[9], nullptr, OFF, 128, 64, 2);
    fused_deform<2><<<gd, 256, 0, stream>>>(A1, OFF, Wd2, p[11], A2, nullptr, 128, 128, 0);
    // stage 3
    fused_conv<1, 1><<<g, 256, 0, stream>>>(A2, Wc3, p[13], A1, nullptr, 128, 64, 0);
    fused_conv<1, 1><<<g, 256, 0, stream>>>(A1, Wo3, p[15], nullptr, OFF, 64, 64, 2);
    fused_deform<1><<<gd, 256, 0, stream>>>(A1, OFF, Wd3, p[17], nullptr, (float*)d_out, 64, 64, 1);
}

// Round 9
// 498.557 us; speedup vs baseline: 1.7774x; 1.0144x over previous
//
#include <hip/hip_runtime.h>
#include <hip/hip_bf16.h>

#define HW 128
#define HW2 16384
#define NEG 0.2f

typedef __attribute__((ext_vector_type(8))) short short8;
typedef __attribute__((ext_vector_type(4))) float f32x4;

__device__ __forceinline__ float lrelu(float v) { return v >= 0.f ? v : NEG * v; }
__device__ __forceinline__ unsigned short f2bf(float f) {
    unsigned int u = __float_as_uint(f);
    u = (u + 0x7fffu + ((u >> 16) & 1u)) >> 16;
    return (unsigned short)u;
}
__device__ __forceinline__ unsigned int pk2(float a, float b) {
    __hip_bfloat162 h = __float22bfloat162_rn(float2{a, b});
    return *(unsigned int*)&h;
}
__device__ __forceinline__ float2 upk(unsigned int u) {
    return float2{__uint_as_float(u << 16), __uint_as_float(u & 0xffff0000u)};
}

// ---------------------------------------------------------------------------
// Weight repack fp32 [M][Cin][3][3] -> bf16 [Mpad][Kpad], Kpad=(Cin/8)*96,
// k-order TAP-MAJOR: k = g*96 + tap*8 + cl, taps 9..11 zero, rows>=validM zero.
// ---------------------------------------------------------------------------
struct WSeg { const float* s; unsigned short* d; int K9; int Kpad; int validM; int n; };
struct WArgs { WSeg seg[9]; };

__global__ void wrepack_kernel(WArgs a)
{
    const WSeg sg = a.seg[blockIdx.y];
    int i = blockIdx.x * 256 + threadIdx.x;
    if (i >= sg.n) return;
    int co = i / sg.Kpad, r = i - co * sg.Kpad;
    int g = r / 96, q = r - g * 96;
    int tap = q >> 3, cl = q & 7;
    unsigned short v = 0;
    if (co < sg.validM && tap < 9)
        v = f2bf(sg.s[(size_t)co * sg.K9 + (g * 8 + cl) * 9 + tap]);
    sg.d[i] = v;
}

// ---------------------------------------------------------------------------
// Fused plain conv (N=64 tile, 2x32) — unchanged (proven in R6).
// ---------------------------------------------------------------------------
template <int MTW, int SRCF>
__global__ __launch_bounds__(256, 4) void fused_conv(
    const void* __restrict__ actv, const unsigned short* __restrict__ wpad,
    const float* __restrict__ bias, unsigned short* __restrict__ outb,
    float* __restrict__ outf, int Cin, int Cout, int mode)
{
    constexpr int SMB = 64 * 136 * 2;
    __shared__ char smem[SMB];
    unsigned short* patch = (unsigned short*)smem;   // [136 px][8ch]
    unsigned short* Es = (unsigned short*)smem;

    const int t = threadIdx.x;
    const int tile = blockIdx.x, b = blockIdx.z;
    const int lane = t & 63, wv = t >> 6, quad = lane >> 4, l15 = lane & 15;
    const int y0 = (tile >> 2) * 2, x0 = (tile & 3) * 32;
    const int Kpad = (Cin >> 3) * 96;
    const int ngrp = Cin >> 3;

    const int pr = t / 34, pc = t - 34 * pr;
    const int gy = y0 - 1 + pr, gx = x0 - 1 + pc;
    const bool pok = (t < 136) && gy >= 0 && gy < HW && gx >= 0 && gx < HW;
    const int gp = pok ? gy * HW + gx : 0;

    const float* actf = (const float*)actv;
    const unsigned short* acth = (const unsigned short*)actv;
    const size_t bofs = (size_t)b * Cin * HW2;

    int baddr[3][4];
#pragma unroll
    for (int st = 0; st < 3; ++st) {
        int tap = st * 4 + quad; tap = tap > 8 ? 8 : tap;
        int ky = (tap * 11) >> 5, kx = tap - 3 * ky;
#pragma unroll
        for (int nt = 0; nt < 4; ++nt) {
            int p = nt * 16 + l15, ly = p >> 5, lx = p & 31;
            baddr[st][nt] = ((ly + ky) * 34 + lx + kx) * 16;
        }
    }
    size_t aoff[MTW];
#pragma unroll
    for (int m = 0; m < MTW; ++m)
        aoff[m] = (size_t)((wv * MTW + m) * 16 + l15) * Kpad + quad * 8;

    f32x4 acc[MTW][4];
#pragma unroll
    for (int m = 0; m < MTW; ++m)
#pragma unroll
        for (int nt = 0; nt < 4; ++nt) acc[m][nt] = (f32x4)(0.f);

    auto load_grp = [&](int g) -> uint4 {
        uint4 u; u.x = u.y = u.z = u.w = 0;
        if (!pok) return u;
        if (SRCF == 1) {
            u = *(const uint4*)(acth + bofs + ((size_t)g * HW2 + gp) * 8);
        } else {
            const float* pl = actf + bofs + (size_t)(g * 8) * HW2 + gp;
            float v0 = pl[0], v1 = pl[HW2], v2 = pl[2 * HW2], v3 = pl[3 * HW2];
            float v4 = pl[4 * HW2], v5 = pl[5 * HW2], v6 = pl[6 * HW2], v7 = pl[7 * HW2];
            u.x = pk2(v0, v1); u.y = pk2(v2, v3);
            u.z = pk2(v4, v5); u.w = pk2(v6, v7);
        }
        return u;
    };

    uint4 cur = load_grp(0);
    for (int g = 0; g < ngrp; ++g) {
        if (t < 136) *(uint4*)(patch + t * 8) = cur;
        __syncthreads();
        uint4 nxt = cur;
        if (g + 1 < ngrp) nxt = load_grp(g + 1);

        const unsigned short* wg = wpad + g * 96;
#pragma unroll
        for (int st = 0; st < 3; ++st) {
            short8 bfr[4];
#pragma unroll
            for (int nt = 0; nt < 4; ++nt)
                bfr[nt] = *(const short8*)((char*)patch + baddr[st][nt]);
#pragma unroll
            for (int m = 0; m < MTW; ++m) {
                short8 a = *(const short8*)(wg + aoff[m] + st * 32);
#pragma unroll
                for (int nt = 0; nt < 4; ++nt)
                    acc[m][nt] = __builtin_amdgcn_mfma_f32_16x16x32_bf16(
                        a, bfr[nt], acc[m][nt], 0, 0, 0);
            }
        }
        __syncthreads();
        cur = nxt;
    }

    if (mode == 0) {
        constexpr int ESTR = 136;
#pragma unroll
        for (int m = 0; m < MTW; ++m) {
            int cb = (wv * MTW + m) * 16;
#pragma unroll
            for (int nt = 0; nt < 4; ++nt) {
                int px = nt * 16 + l15;
                int co = cb + quad * 4;
                unsigned int u0 = pk2(lrelu(acc[m][nt][0] + bias[co]),
                                      lrelu(acc[m][nt][1] + bias[co + 1]));
                unsigned int u1 = pk2(lrelu(acc[m][nt][2] + bias[co + 2]),
                                      lrelu(acc[m][nt][3] + bias[co + 3]));
                uint2 u; u.x = u0; u.y = u1;
                *(uint2*)&Es[px * ESTR + co] = u;
            }
        }
        __syncthreads();
        const int ng8 = Cout >> 3;
        unsigned short* ob = outb + (size_t)b * Cout * HW2;
        for (int tt = t; tt < 64 * ng8; tt += 256) {
            int cg = tt >> 6, px = tt & 63;
            int gp2 = (y0 + (px >> 5)) * HW + x0 + (px & 31);
            *(uint4*)(ob + ((size_t)cg * HW2 + gp2) * 8) =
                *(const uint4*)&Es[px * ESTR + cg * 8];
        }
    } else {
        float* of = outf + (size_t)b * 18 * HW2;
#pragma unroll
        for (int m = 0; m < MTW; ++m) {
            int cb = (wv * MTW + m) * 16;
#pragma unroll
            for (int nt = 0; nt < 4; ++nt) {
                int px = nt * 16 + l15;
                int gp2 = (y0 + (px >> 5)) * HW + x0 + (px & 31);
#pragma unroll
                for (int r = 0; r < 4; ++r) {
                    int co = cb + quad * 4 + r;
                    if (co < 18)
                        of[(size_t)co * HW2 + gp2] = acc[m][nt][r] + bias[co];
                }
            }
        }
    }
}

// ---------------------------------------------------------------------------
// Fused deformable conv, N=32 (2x16 px), 2048 blocks (8/CU), HYBRID:
// R8's register discipline + R6's register prefetch. Patch shrunk to
// 10x25 = 250 px so ONE uint4 register slot stages the whole patch
// (loads for g+1 issued right after the patch barrier -> full overlap
// across col-build + MFMA). 2 barriers/group. LDS ~10.4 KB.
// mode 0: NHWC8 bf16 out + leaky; mode 1: planar fp32 out + leaky.
// ---------------------------------------------------------------------------
template <int MTW>
__global__ __launch_bounds__(256, 8) void fused_deform(
    const unsigned short* __restrict__ acth, const float* __restrict__ off,
    const unsigned short* __restrict__ wpad, const float* __restrict__ bias,
    unsigned short* __restrict__ outb, float* __restrict__ outf,
    int Cin, int Cout, int mode)
{
    constexpr int PATW = 25, PATP = 250;                 // 10 rows x 25 cols
    constexpr int CSTR = 104;
    constexpr int SMB1 = PATP * 16 + 32 * CSTR * 2;      // 4000 + 6656 = 10656
    constexpr int SMB2 = 32 * 136 * 2;                   // Es 8704
    constexpr int SMB = SMB1 > SMB2 ? SMB1 : SMB2;
    __shared__ char smem[SMB];
    unsigned short* patch = (unsigned short*)smem;       // [250 px][8ch]
    unsigned short* Cs = (unsigned short*)(smem + PATP * 16);
    unsigned short* Es = (unsigned short*)smem;

    const int t = threadIdx.x;
    const int tile = blockIdx.x, b = blockIdx.z;
    const int lane = t & 63, wv = t >> 6, quad = lane >> 4, l15 = lane & 15;
    const int y0 = (tile >> 3) * 2, x0 = (tile & 7) * 16;
    const int Kpad = (Cin >> 3) * 96;
    const int ngrp = Cin >> 3;
    const int py0 = y0 - 4, px0 = x0 - 4;

    // zero Cs k-pad [72,96): 32 rows x 3 uint4
    if (t < 96) {
        int p = t / 3, j = t - 3 * p;
        uint4 z; z.x = z.y = z.z = z.w = 0;
        *(uint4*)&Cs[p * CSTR + 72 + j * 8] = z;
    }

    // ---- phase 0: fast-path tap params (slots t, t+256) ----
    float w00[2], w01[2], w10[2], w11[2];
    int pbase[2], csad[2], svalid[2];
    int allin = 1;
    {
        const float* offb = off + (size_t)b * 18 * HW2;
#pragma unroll
        for (int s = 0; s < 2; ++s) {
            int task = t + s * 256;
            svalid[s] = task < 288;
            int task2 = svalid[s] ? task : 0;
            int p = task2 / 9, k = task2 - 9 * p;
            int yy = y0 + (p >> 4), xx = x0 + (p & 15);
            float dy = offb[(2 * k) * HW2 + yy * HW + xx];
            float dx = offb[(2 * k + 1) * HW2 + yy * HW + xx];
            float py = (float)(yy + k / 3 - 1) + dy;
            float px = (float)(xx + k % 3 - 1) + dx;
            float fy = floorf(py), fx = floorf(px);
            float wy = py - fy, wx = px - fx;
            int iy = (int)fy, ix = (int)fx;
            w00[s] = (1.f - wy) * (1.f - wx);
            w01[s] = (1.f - wy) * wx;
            w10[s] = wy * (1.f - wx);
            w11[s] = wy * wx;
            pbase[s] = ((iy - py0) * PATW + (ix - px0)) * 16;     // bytes
            csad[s] = (p * CSTR + k * 8) * 2;                     // bytes
            // patch covers rows py0..py0+9, cols px0..px0+24
            bool ip = iy >= py0 && iy + 1 <= y0 + 5 && ix >= px0 && ix + 1 <= x0 + 20;
            if (!ip) allin = 0;
        }
    }
    const int fast = __syncthreads_and(allin);

    // staging geometry: one slot, t < 250
    const int r0 = t / PATW, c0_ = t - PATW * r0;
    const int gy0_ = py0 + r0, gx0_ = px0 + c0_;
    const bool ok0 = (t < PATP) && gy0_ >= 0 && gy0_ < HW && gx0_ >= 0 && gx0_ < HW;
    const int go0 = ok0 ? gy0_ * HW + gx0_ : 0;

    const size_t bofs = (size_t)b * Cin * HW2;

    size_t aoff[MTW];
#pragma unroll
    for (int m = 0; m < MTW; ++m)
        aoff[m] = (size_t)((wv * MTW + m) * 16 + l15) * Kpad + quad * 8;
    const int bb0 = l15 * (CSTR * 2) + quad * 16;        // B-frag base (bytes)
    const int bb1 = bb0 + 16 * (CSTR * 2);

    f32x4 acc[MTW][2];
#pragma unroll
    for (int m = 0; m < MTW; ++m)
#pragma unroll
        for (int nt = 0; nt < 2; ++nt) acc[m][nt] = (f32x4)(0.f);

    if (fast) {
        uint4 u0; u0.x = u0.y = u0.z = u0.w = 0;
        if (ok0) u0 = *(const uint4*)(acth + bofs + (size_t)go0 * 8);

        for (int g = 0; g < ngrp; ++g) {
            if (t < PATP) *(uint4*)(patch + t * 8) = u0;
            __syncthreads();

            // issue next-group loads NOW — in flight across col build + MFMA
            if (g + 1 < ngrp) {
                u0.x = u0.y = u0.z = u0.w = 0;
                if (ok0) u0 = *(const uint4*)(acth + bofs +
                                              ((size_t)(g + 1) * HW2 + go0) * 8);
            }

            // col build: sequential corner accumulation
#pragma unroll
            for (int s = 0; s < 2; ++s) {
                if (!svalid[s]) continue;
                const char* base = (const char*)patch + pbase[s];
                float f0, f1, f2, f3, f4, f5, f6, f7;
                {
                    uint4 c = *(const uint4*)base;
                    float2 p0 = upk(c.x), p1 = upk(c.y), p2 = upk(c.z), p3 = upk(c.w);
                    float w = w00[s];
                    f0 = w * p0.x; f1 = w * p0.y; f2 = w * p1.x; f3 = w * p1.y;
                    f4 = w * p2.x; f5 = w * p2.y; f6 = w * p3.x; f7 = w * p3.y;
                }
                {
                    uint4 c = *(const uint4*)(base + 16);
                    float2 p0 = upk(c.x), p1 = upk(c.y), p2 = upk(c.z), p3 = upk(c.w);
                    float w = w01[s];
                    f0 += w * p0.x; f1 += w * p0.y; f2 += w * p1.x; f3 += w * p1.y;
                    f4 += w * p2.x; f5 += w * p2.y; f6 += w * p3.x; f7 += w * p3.y;
                }
                {
                    uint4 c = *(const uint4*)(base + PATW * 16);
                    float2 p0 = upk(c.x), p1 = upk(c.y), p2 = upk(c.z), p3 = upk(c.w);
                    float w = w10[s];
                    f0 += w * p0.x; f1 += w * p0.y; f2 += w * p1.x; f3 += w * p1.y;
                    f4 += w * p2.x; f5 += w * p2.y; f6 += w * p3.x; f7 += w * p3.y;
                }
                {
                    uint4 c = *(const uint4*)(base + PATW * 16 + 16);
                    float2 p0 = upk(c.x), p1 = upk(c.y), p2 = upk(c.z), p3 = upk(c.w);
                    float w = w11[s];
                    f0 += w * p0.x; f1 += w * p0.y; f2 += w * p1.x; f3 += w * p1.y;
                    f4 += w * p2.x; f5 += w * p2.y; f6 += w * p3.x; f7 += w * p3.y;
                }
                uint4 ou;
                ou.x = pk2(f0, f1); ou.y = pk2(f2, f3);
                ou.z = pk2(f4, f5); ou.w = pk2(f6, f7);
                *(uint4*)((char*)Cs + csad[s]) = ou;
            }
            __syncthreads();

            const unsigned short* wg = wpad + g * 96;
#pragma unroll
            for (int st = 0; st < 3; ++st) {
                short8 b0 = *(const short8*)((char*)Cs + bb0 + st * 64);
                short8 b1 = *(const short8*)((char*)Cs + bb1 + st * 64);
#pragma unroll
                for (int m = 0; m < MTW; ++m) {
                    short8 a = *(const short8*)(wg + aoff[m] + st * 32);
                    acc[m][0] = __builtin_amdgcn_mfma_f32_16x16x32_bf16(a, b0, acc[m][0], 0, 0, 0);
                    acc[m][1] = __builtin_amdgcn_mfma_f32_16x16x32_bf16(a, b1, acc[m][1], 0, 0, 0);
                }
            }
            // no barrier here: next patch write races nothing (all waves must
            // pass the top barrier, which requires finishing this MFMA section)
        }
    } else {
        // slow path: recompute taps per group; global corner reads.
        const float* offb = off + (size_t)b * 18 * HW2;
        for (int g = 0; g < ngrp; ++g) {
            const unsigned short* gb = acth + bofs + (size_t)g * HW2 * 8;
#pragma unroll
            for (int s = 0; s < 2; ++s) {
                if (!svalid[s]) continue;
                int task = t + s * 256;
                int p = task / 9, k = task - 9 * p;
                int yy = y0 + (p >> 4), xx = x0 + (p & 15);
                float dy = offb[(2 * k) * HW2 + yy * HW + xx];
                float dx = offb[(2 * k + 1) * HW2 + yy * HW + xx];
                float py = (float)(yy + k / 3 - 1) + dy;
                float px = (float)(xx + k % 3 - 1) + dx;
                float fy = floorf(py), fx = floorf(px);
                float wy = py - fy, wx = px - fx;
                int iy = (int)fy, ix = (int)fx;
                float f0 = 0, f1 = 0, f2 = 0, f3 = 0, f4 = 0, f5 = 0, f6 = 0, f7 = 0;
#pragma unroll
                for (int q = 0; q < 4; ++q) {
                    int ddy = q >> 1, ddx = q & 1;
                    int sy = iy + ddy, sx = ix + ddx;
                    float w = (ddy ? wy : 1.f - wy) * (ddx ? wx : 1.f - wx);
                    if (sy < 0 || sy >= HW || sx < 0 || sx >= HW) w = 0.f;
                    int cy = min(max(sy, 0), HW - 1), cx = min(max(sx, 0), HW - 1);
                    uint4 c = *(const uint4*)(gb + (size_t)(cy * HW + cx) * 8);
                    float2 p0 = upk(c.x), p1 = upk(c.y), p2 = upk(c.z), p3 = upk(c.w);
                    f0 += w * p0.x; f1 += w * p0.y; f2 += w * p1.x; f3 += w * p1.y;
                    f4 += w * p2.x; f5 += w * p2.y; f6 += w * p3.x; f7 += w * p3.y;
                }
                uint4 ou;
                ou.x = pk2(f0, f1); ou.y = pk2(f2, f3);
                ou.z = pk2(f4, f5); ou.w = pk2(f6, f7);
                *(uint4*)((char*)Cs + csad[s]) = ou;
            }
            __syncthreads();

            const unsigned short* wg = wpad + g * 96;
#pragma unroll
            for (int st = 0; st < 3; ++st) {
                short8 b0 = *(const short8*)((char*)Cs + bb0 + st * 64);
                short8 b1 = *(const short8*)((char*)Cs + bb1 + st * 64);
#pragma unroll
                for (int m = 0; m < MTW; ++m) {
                    short8 a = *(const short8*)(wg + aoff[m] + st * 32);
                    acc[m][0] = __builtin_amdgcn_mfma_f32_16x16x32_bf16(a, b0, acc[m][0], 0, 0, 0);
                    acc[m][1] = __builtin_amdgcn_mfma_f32_16x16x32_bf16(a, b1, acc[m][1], 0, 0, 0);
                }
            }
            __syncthreads();
        }
    }

    // ---- epilogue ----
    if (mode == 0) {
        __syncthreads();   // Es aliases patch/Cs — make sure K-loop fully done
        constexpr int ESTR = 136;
#pragma unroll
        for (int m = 0; m < MTW; ++m) {
            int cb = (wv * MTW + m) * 16;
#pragma unroll
            for (int nt = 0; nt < 2; ++nt) {
                int px = nt * 16 + l15;
                int co = cb + quad * 4;
                unsigned int u0 = pk2(lrelu(acc[m][nt][0] + bias[co]),
                                      lrelu(acc[m][nt][1] + bias[co + 1]));
                unsigned int u1 = pk2(lrelu(acc[m][nt][2] + bias[co + 2]),
                                      lrelu(acc[m][nt][3] + bias[co + 3]));
                uint2 u; u.x = u0; u.y = u1;
                *(uint2*)&Es[px * ESTR + co] = u;
            }
        }
        __syncthreads();
        const int ng8 = Cout >> 3;
        unsigned short* ob = outb + (size_t)b * Cout * HW2;
        for (int tt = t; tt < 32 * ng8; tt += 256) {
            int cg = tt >> 5, px = tt & 31;
            int gp2 = (y0 + (px >> 4)) * HW + x0 + (px & 15);
            *(uint4*)(ob + ((size_t)cg * HW2 + gp2) * 8) =
                *(const uint4*)&Es[px * ESTR + cg * 8];
        }
    } else {
        float* of = outf + (size_t)b * Cout * HW2;
#pragma unroll
        for (int m = 0; m < MTW; ++m) {
            int cb = (wv * MTW + m) * 16;
#pragma unroll
            for (int nt = 0; nt < 2; ++nt) {
                int px = nt * 16 + l15;
                int gp2 = (y0 + (px >> 4)) * HW + x0 + (px & 15);
#pragma unroll
                for (int r = 0; r < 4; ++r) {
                    int co = cb + quad * 4 + r;
                    of[(size_t)co * HW2 + gp2] = lrelu(acc[m][nt][r] + bias[co]);
                }
            }
        }
    }
}

// ---------------------------------------------------------------------------
extern "C" void kernel_launch(void* const* d_in, const int* in_sizes, int n_in,
                              void* d_out, int out_size, void* d_ws,
                              size_t ws_size, hipStream_t stream)
{
    const float* x = (const float*)d_in[0];
    const float* p[18];
    for (int i = 0; i < 18; ++i) p[i] = (const float*)d_in[1 + i];

    char* ws = (char*)d_ws;
    unsigned short* A1 = (unsigned short*)ws;              // NHWC8 bf16
    unsigned short* A2 = (unsigned short*)(ws + 16777216);
    float* OFF = (float*)(ws + 33554432);                  // fp32 planar 18ch
    unsigned short* WB = (unsigned short*)(ws + 38273024);

    unsigned short* Wc1 = WB;             // 128 x 768
    unsigned short* Wo1 = Wc1 + 98304;    // 64  x 1536 (18 valid)
    unsigned short* Wd1 = Wo1 + 98304;    // 128 x 1536
    unsigned short* Wc2 = Wd1 + 196608;   // 128 x 1536
    unsigned short* Wo2 = Wc2 + 196608;   // 64  x 1536 (18 valid)
    unsigned short* Wd2 = Wo2 + 98304;    // 128 x 1536
    unsigned short* Wc3 = Wd2 + 196608;   // 64  x 1536
    unsigned short* Wo3 = Wc3 + 98304;    // 64  x 768  (18 valid)
    unsigned short* Wd3 = Wo3 + 49152;    // 64  x 768

    WArgs wa;
    wa.seg[0] = {p[0],  Wc1,  576,  768, 128,  98304};
    wa.seg[1] = {p[2],  Wo1, 1152, 1536,  18,  98304};
    wa.seg[2] = {p[4],  Wd1, 1152, 1536, 128, 196608};
    wa.seg[3] = {p[6],  Wc2, 1152, 1536, 128, 196608};
    wa.seg[4] = {p[8],  Wo2, 1152, 1536,  18,  98304};
    wa.seg[5] = {p[10], Wd2, 1152, 1536, 128, 196608};
    wa.seg[6] = {p[12], Wc3, 1152, 1536,  64,  98304};
    wa.seg[7] = {p[14], Wo3,  576,  768,  18,  49152};
    wa.seg[8] = {p[16], Wd3,  576,  768,  64,  49152};
    wrepack_kernel<<<dim3(768, 9), 256, 0, stream>>>(wa);

    dim3 g(256, 1, 4);      // conv grid: 2x32 tiles
    dim3 gd(512, 1, 4);     // deform grid: 2x16 tiles
    // stage 1
    fused_conv<2, 0><<<g, 256, 0, stream>>>(x, Wc1, p[1], A1, nullptr, 64, 128, 0);
    fused_conv<1, 1><<<g, 256, 0, stream>>>(A1, Wo1, p[3], nullptr, OFF, 128, 64, 2);
    fused_deform<2><<<gd, 256, 0, stream>>>(A1, OFF, Wd1, p[5], A2, nullptr, 128, 128, 0);
    // stage 2
    fused_conv<2, 1><<<g, 256, 0, stream>>>(A2, Wc2, p[7], A1, nullptr, 128, 128, 0);
    fused_conv<1, 1><<<g, 256, 0, stream>>>(A1, Wo2, p[9], nullptr, OFF, 128, 64, 2);
    fused_deform<2><<<gd, 256, 0, stream>>>(A1, OFF, Wd2, p[11], A2, nullptr, 128, 128, 0);
    // stage 3
    fused_conv<1, 1><<<g, 256, 0, stream>>>(A2, Wc3, p[13], A1, nullptr, 128, 64, 0);
    fused_conv<1, 1><<<g, 256, 0, stream>>>(A1, Wo3, p[15], nullptr, OFF, 64, 64, 2);
    fused_deform<1><<<gd, 256, 0, stream>>>(A1, OFF, Wd3, p[17], nullptr, (float*)d_out, 64, 64, 1);
}

// Round 11
// 420.656 us; speedup vs baseline: 2.1065x; 1.1852x over previous
//
#include <hip/hip_runtime.h>
#include <hip/hip_bf16.h>

#define HW 128
#define HW2 16384
#define NEG 0.2f

typedef __attribute__((ext_vector_type(8))) short short8;
typedef __attribute__((ext_vector_type(4))) float f32x4;

__device__ __forceinline__ float lrelu(float v) { return v >= 0.f ? v : NEG * v; }
__device__ __forceinline__ unsigned short f2bf(float f) {
    unsigned int u = __float_as_uint(f);
    u = (u + 0x7fffu + ((u >> 16) & 1u)) >> 16;
    return (unsigned short)u;
}
__device__ __forceinline__ unsigned int pk2(float a, float b) {
    __hip_bfloat162 h = __float22bfloat162_rn(float2{a, b});
    return *(unsigned int*)&h;
}
__device__ __forceinline__ float2 upk(unsigned int u) {
    return float2{__uint_as_float(u << 16), __uint_as_float(u & 0xffff0000u)};
}

// ---------------------------------------------------------------------------
// Weight repack fp32 [M][Cin][3][3] -> bf16 [Mpad][Kpad], Kpad=(Cin/8)*96,
// k-order TAP-MAJOR: k = g*96 + tap*8 + cl, taps 9..11 zero, rows>=validM zero.
// ---------------------------------------------------------------------------
struct WSeg { const float* s; unsigned short* d; int K9; int Kpad; int validM; int n; };
struct WArgs { WSeg seg[9]; };

__global__ void wrepack_kernel(WArgs a)
{
    const WSeg sg = a.seg[blockIdx.y];
    int i = blockIdx.x * 256 + threadIdx.x;
    if (i >= sg.n) return;
    int co = i / sg.Kpad, r = i - co * sg.Kpad;
    int g = r / 96, q = r - g * 96;
    int tap = q >> 3, cl = q & 7;
    unsigned short v = 0;
    if (co < sg.validM && tap < 9)
        v = f2bf(sg.s[(size_t)co * sg.K9 + (g * 8 + cl) * 9 + tap]);
    sg.d[i] = v;
}

// ---------------------------------------------------------------------------
// Fused plain conv (N=64 tile, 2x32), SINGLE barrier per group:
// double-buffered patch; MFMA(g) reads patch[g&1] while patch[(g+1)&1] is
// written from prefetch regs and g+2 loads are issued.
// ---------------------------------------------------------------------------
template <int MTW, int SRCF>
__global__ __launch_bounds__(256, 4) void fused_conv(
    const void* __restrict__ actv, const unsigned short* __restrict__ wpad,
    const float* __restrict__ bias, unsigned short* __restrict__ outb,
    float* __restrict__ outf, int Cin, int Cout, int mode)
{
    constexpr int PB = 136 * 16;                 // 2176 B per patch buffer
    constexpr int SMB = 64 * 136 * 2;            // Es (17408) > 2*PB
    __shared__ char smem[SMB];
    unsigned short* Es = (unsigned short*)smem;

    const int t = threadIdx.x;
    const int tile = blockIdx.x, b = blockIdx.z;
    const int lane = t & 63, wv = t >> 6, quad = lane >> 4, l15 = lane & 15;
    const int y0 = (tile >> 2) * 2, x0 = (tile & 3) * 32;
    const int Kpad = (Cin >> 3) * 96;
    const int ngrp = Cin >> 3;

    const int pr = t / 34, pc = t - 34 * pr;
    const int gy = y0 - 1 + pr, gx = x0 - 1 + pc;
    const bool pok = (t < 136) && gy >= 0 && gy < HW && gx >= 0 && gx < HW;
    const int gp = pok ? gy * HW + gx : 0;

    const float* actf = (const float*)actv;
    const unsigned short* acth = (const unsigned short*)actv;
    const size_t bofs = (size_t)b * Cin * HW2;

    int baddr[3][4];
#pragma unroll
    for (int st = 0; st < 3; ++st) {
        int tap = st * 4 + quad; tap = tap > 8 ? 8 : tap;
        int ky = (tap * 11) >> 5, kx = tap - 3 * ky;
#pragma unroll
        for (int nt = 0; nt < 4; ++nt) {
            int p = nt * 16 + l15, ly = p >> 5, lx = p & 31;
            baddr[st][nt] = ((ly + ky) * 34 + lx + kx) * 16;
        }
    }
    size_t aoff[MTW];
#pragma unroll
    for (int m = 0; m < MTW; ++m)
        aoff[m] = (size_t)((wv * MTW + m) * 16 + l15) * Kpad + quad * 8;

    f32x4 acc[MTW][4];
#pragma unroll
    for (int m = 0; m < MTW; ++m)
#pragma unroll
        for (int nt = 0; nt < 4; ++nt) acc[m][nt] = (f32x4)(0.f);

    auto load_grp = [&](int g) -> uint4 {
        uint4 u; u.x = u.y = u.z = u.w = 0;
        if (!pok) return u;
        if (SRCF == 1) {
            u = *(const uint4*)(acth + bofs + ((size_t)g * HW2 + gp) * 8);
        } else {
            const float* pl = actf + bofs + (size_t)(g * 8) * HW2 + gp;
            float v0 = pl[0], v1 = pl[HW2], v2 = pl[2 * HW2], v3 = pl[3 * HW2];
            float v4 = pl[4 * HW2], v5 = pl[5 * HW2], v6 = pl[6 * HW2], v7 = pl[7 * HW2];
            u.x = pk2(v0, v1); u.y = pk2(v2, v3);
            u.z = pk2(v4, v5); u.w = pk2(v6, v7);
        }
        return u;
    };

    uint4 cur = load_grp(0);
    if (t < 136) *(uint4*)(smem + t * 16) = cur;          // patch buf 0
    if (ngrp > 1) cur = load_grp(1);
    __syncthreads();

    for (int g = 0; g < ngrp; ++g) {
        char* pb = smem + (g & 1) * PB;
        const unsigned short* wg = wpad + g * 96;
#pragma unroll
        for (int st = 0; st < 3; ++st) {
            short8 bfr[4];
#pragma unroll
            for (int nt = 0; nt < 4; ++nt)
                bfr[nt] = *(const short8*)(pb + baddr[st][nt]);
#pragma unroll
            for (int m = 0; m < MTW; ++m) {
                short8 a = *(const short8*)(wg + aoff[m] + st * 32);
#pragma unroll
                for (int nt = 0; nt < 4; ++nt)
                    acc[m][nt] = __builtin_amdgcn_mfma_f32_16x16x32_bf16(
                        a, bfr[nt], acc[m][nt], 0, 0, 0);
            }
        }
        if (g + 1 < ngrp) {
            if (t < 136) *(uint4*)(smem + ((g + 1) & 1) * PB + t * 16) = cur;
            if (g + 2 < ngrp) cur = load_grp(g + 2);
        }
        __syncthreads();
    }

    if (mode == 0) {
        constexpr int ESTR = 136;
#pragma unroll
        for (int m = 0; m < MTW; ++m) {
            int cb = (wv * MTW + m) * 16;
#pragma unroll
            for (int nt = 0; nt < 4; ++nt) {
                int px = nt * 16 + l15;
                int co = cb + quad * 4;
                unsigned int u0 = pk2(lrelu(acc[m][nt][0] + bias[co]),
                                      lrelu(acc[m][nt][1] + bias[co + 1]));
                unsigned int u1 = pk2(lrelu(acc[m][nt][2] + bias[co + 2]),
                                      lrelu(acc[m][nt][3] + bias[co + 3]));
                uint2 u; u.x = u0; u.y = u1;
                *(uint2*)&Es[px * ESTR + co] = u;
            }
        }
        __syncthreads();
        const int ng8 = Cout >> 3;
        unsigned short* ob = outb + (size_t)b * Cout * HW2;
        for (int tt = t; tt < 64 * ng8; tt += 256) {
            int cg = tt >> 6, px = tt & 63;
            int gp2 = (y0 + (px >> 5)) * HW + x0 + (px & 31);
            *(uint4*)(ob + ((size_t)cg * HW2 + gp2) * 8) =
                *(const uint4*)&Es[px * ESTR + cg * 8];
        }
    } else {
        float* of = outf + (size_t)b * 18 * HW2;
#pragma unroll
        for (int m = 0; m < MTW; ++m) {
            int cb = (wv * MTW + m) * 16;
#pragma unroll
            for (int nt = 0; nt < 4; ++nt) {
                int px = nt * 16 + l15;
                int gp2 = (y0 + (px >> 5)) * HW + x0 + (px & 31);
#pragma unroll
                for (int r = 0; r < 4; ++r) {
                    int co = cb + quad * 4 + r;
                    if (co < 18)
                        of[(size_t)co * HW2 + gp2] = acc[m][nt][r] + bias[co];
                }
            }
        }
    }
}

// ---------------------------------------------------------------------------
// Fused deformable conv, N=64 (2x32 px), SOFTWARE-PIPELINED:
// patch AND Cs double-buffered -> ONE barrier per group; iteration body
// issues MFMA(g-1) (reads Cs[(g-1)&1]) alongside col-build(g) (writes
// Cs[g&1]) so MFMA and VALU pipes co-issue (m114). LDS 39.7 KB -> 4 bl/CU.
// mode 0: NHWC8 bf16 out + leaky; mode 1: planar fp32 out + leaky.
// ---------------------------------------------------------------------------
template <int MTW>
__global__ __launch_bounds__(256, 4) void fused_deform(
    const unsigned short* __restrict__ acth, const float* __restrict__ off,
    const unsigned short* __restrict__ wpad, const float* __restrict__ bias,
    unsigned short* __restrict__ outb, float* __restrict__ outf,
    int Cin, int Cout, int mode)
{
    constexpr int PATW = 41, PATP = 410;
    constexpr int CSTR = 104;
    constexpr int PB = PATP * 16;                 // 6560 B
    constexpr int CB = 64 * CSTR * 2;             // 13312 B
    constexpr int SMB = 2 * PB + 2 * CB;          // 39744 B
    __shared__ char smem[SMB];
    unsigned short* Es = (unsigned short*)smem;   // epilogue alias (17408 B)

    const int t = threadIdx.x;
    const int tile = blockIdx.x, b = blockIdx.z;
    const int lane = t & 63, wv = t >> 6, quad = lane >> 4, l15 = lane & 15;
    const int y0 = (tile >> 2) * 2, x0 = (tile & 3) * 32;
    const int Kpad = (Cin >> 3) * 96;
    const int ngrp = Cin >> 3;
    const int py0 = y0 - 4, px0 = x0 - 4;

    // zero Cs k-pad [72,96) in BOTH buffers: 2 bufs x 64 rows x 3 uint4 = 384
    for (int i = t; i < 384; i += 256) {
        int bu = i / 192;              // buffer 0 or 1
        int ii = i - 192 * bu;         // 0..191
        int p = ii / 3, j = ii - 3 * p;
        uint4 z; z.x = z.y = z.z = z.w = 0;
        *(uint4*)(smem + 2 * PB + bu * CB + (p * CSTR + 72 + j * 8) * 2) = z;
    }

    // ---- phase 0: fast-path tap params (slots t, t+256, t+512) ----
    float w00[3], w01[3], w10[3], w11[3];
    int pbase[3], csad[3], svalid[3];
    int allin = 1;
    {
        const float* offb = off + (size_t)b * 18 * HW2;
#pragma unroll
        for (int s = 0; s < 3; ++s) {
            int task = t + s * 256;
            svalid[s] = task < 576;
            int task2 = svalid[s] ? task : 0;
            int p = task2 / 9, k = task2 - 9 * p;
            int yy = y0 + (p >> 5), xx = x0 + (p & 31);
            float dy = offb[(2 * k) * HW2 + yy * HW + xx];
            float dx = offb[(2 * k + 1) * HW2 + yy * HW + xx];
            float py = (float)(yy + k / 3 - 1) + dy;
            float px = (float)(xx + k % 3 - 1) + dx;
            float fy = floorf(py), fx = floorf(px);
            float wy = py - fy, wx = px - fx;
            int iy = (int)fy, ix = (int)fx;
            w00[s] = (1.f - wy) * (1.f - wx);
            w01[s] = (1.f - wy) * wx;
            w10[s] = wy * (1.f - wx);
            w11[s] = wy * wx;
            pbase[s] = ((iy - py0) * PATW + (ix - px0)) * 16;   // bytes
            csad[s] = (p * CSTR + k * 8) * 2;                   // bytes
            bool ip = iy >= py0 && iy + 1 <= y0 + 5 && ix >= px0 && ix + 1 <= x0 + 36;
            if (!ip) allin = 0;
        }
    }
    const int fast = __syncthreads_and(allin);

    // staging: slot0 = t (<410 always), slot1 = t+256 (t<154)
    const int r0 = t / PATW, c0_ = t - PATW * r0;
    const int gy0_ = py0 + r0, gx0_ = px0 + c0_;
    const bool ok0 = gy0_ >= 0 && gy0_ < HW && gx0_ >= 0 && gx0_ < HW;
    const int go0 = ok0 ? gy0_ * HW + gx0_ : 0;
    const int i1 = t + 256;
    const bool has1 = i1 < PATP;
    const int r1 = i1 / PATW, c1_ = i1 - PATW * r1;
    const int gy1_ = py0 + r1, gx1_ = px0 + c1_;
    const bool ok1 = has1 && gy1_ >= 0 && gy1_ < HW && gx1_ >= 0 && gx1_ < HW;
    const int go1 = ok1 ? gy1_ * HW + gx1_ : 0;

    const size_t bofs = (size_t)b * Cin * HW2;

    size_t aoff[MTW];
#pragma unroll
    for (int m = 0; m < MTW; ++m)
        aoff[m] = (size_t)((wv * MTW + m) * 16 + l15) * Kpad + quad * 8;
    const int bb0 = l15 * (CSTR * 2) + quad * 16;   // B-frag byte base in Cs

    f32x4 acc[MTW][4];
#pragma unroll
    for (int m = 0; m < MTW; ++m)
#pragma unroll
        for (int nt = 0; nt < 4; ++nt) acc[m][nt] = (f32x4)(0.f);

    auto mfma_step = [&](const char* cs, const unsigned short* wg) {
#pragma unroll
        for (int st = 0; st < 3; ++st) {
            short8 bfr[4];
#pragma unroll
            for (int nt = 0; nt < 4; ++nt)
                bfr[nt] = *(const short8*)(cs + bb0 + nt * 16 * (CSTR * 2) + st * 64);
#pragma unroll
            for (int m = 0; m < MTW; ++m) {
                short8 a = *(const short8*)(wg + aoff[m] + st * 32);
#pragma unroll
                for (int nt = 0; nt < 4; ++nt)
                    acc[m][nt] = __builtin_amdgcn_mfma_f32_16x16x32_bf16(
                        a, bfr[nt], acc[m][nt], 0, 0, 0);
            }
        }
    };

    if (fast) {
        uint4 u0, u1;
        u0.x = u0.y = u0.z = u0.w = 0; u1 = u0;
        if (ok0) u0 = *(const uint4*)(acth + bofs + (size_t)go0 * 8);
        if (ok1) u1 = *(const uint4*)(acth + bofs + (size_t)go1 * 8);
        *(uint4*)(smem + t * 16) = u0;
        if (has1) *(uint4*)(smem + i1 * 16) = u1;
        if (ngrp > 1) {
            u0.x = u0.y = u0.z = u0.w = 0; u1 = u0;
            if (ok0) u0 = *(const uint4*)(acth + bofs + ((size_t)HW2 + go0) * 8);
            if (ok1) u1 = *(const uint4*)(acth + bofs + ((size_t)HW2 + go1) * 8);
        }
        __syncthreads();

        for (int g = 0; g < ngrp; ++g) {
            const char* pb = smem + (g & 1) * PB;
            char* csW = smem + 2 * PB + (g & 1) * CB;

            // (a) MFMA for previous group — overlaps with col build below
            if (g > 0)
                mfma_step(smem + 2 * PB + ((g - 1) & 1) * CB, wpad + (g - 1) * 96);

            // (b) col build g -> Cs[g&1]
#pragma unroll
            for (int s = 0; s < 3; ++s) {
                if (!svalid[s]) continue;
                const char* base = pb + pbase[s];
                float f0, f1, f2, f3, f4, f5, f6, f7;
                {
                    uint4 c = *(const uint4*)base;
                    float2 p0 = upk(c.x), p1 = upk(c.y), p2 = upk(c.z), p3 = upk(c.w);
                    float w = w00[s];
                    f0 = w * p0.x; f1 = w * p0.y; f2 = w * p1.x; f3 = w * p1.y;
                    f4 = w * p2.x; f5 = w * p2.y; f6 = w * p3.x; f7 = w * p3.y;
                }
                {
                    uint4 c = *(const uint4*)(base + 16);
                    float2 p0 = upk(c.x), p1 = upk(c.y), p2 = upk(c.z), p3 = upk(c.w);
                    float w = w01[s];
                    f0 += w * p0.x; f1 += w * p0.y; f2 += w * p1.x; f3 += w * p1.y;
                    f4 += w * p2.x; f5 += w * p2.y; f6 += w * p3.x; f7 += w * p3.y;
                }
                {
                    uint4 c = *(const uint4*)(base + PATW * 16);
                    float2 p0 = upk(c.x), p1 = upk(c.y), p2 = upk(c.z), p3 = upk(c.w);
                    float w = w10[s];
                    f0 += w * p0.x; f1 += w * p0.y; f2 += w * p1.x; f3 += w * p1.y;
                    f4 += w * p2.x; f5 += w * p2.y; f6 += w * p3.x; f7 += w * p3.y;
                }
                {
                    uint4 c = *(const uint4*)(base + PATW * 16 + 16);
                    float2 p0 = upk(c.x), p1 = upk(c.y), p2 = upk(c.z), p3 = upk(c.w);
                    float w = w11[s];
                    f0 += w * p0.x; f1 += w * p0.y; f2 += w * p1.x; f3 += w * p1.y;
                    f4 += w * p2.x; f5 += w * p2.y; f6 += w * p3.x; f7 += w * p3.y;
                }
                uint4 ou;
                ou.x = pk2(f0, f1); ou.y = pk2(f2, f3);
                ou.z = pk2(f4, f5); ou.w = pk2(f6, f7);
                *(uint4*)(csW + csad[s]) = ou;
            }

            // (c) write patch g+1 from prefetch regs; (d) load g+2
            if (g + 1 < ngrp) {
                char* pn = smem + ((g + 1) & 1) * PB;
                *(uint4*)(pn + t * 16) = u0;
                if (has1) *(uint4*)(pn + i1 * 16) = u1;
                if (g + 2 < ngrp) {
                    u0.x = u0.y = u0.z = u0.w = 0; u1 = u0;
                    if (ok0) u0 = *(const uint4*)(acth + bofs +
                                                  ((size_t)(g + 2) * HW2 + go0) * 8);
                    if (ok1) u1 = *(const uint4*)(acth + bofs +
                                                  ((size_t)(g + 2) * HW2 + go1) * 8);
                }
            }
            __syncthreads();
        }
        // final group's MFMA
        mfma_step(smem + 2 * PB + ((ngrp - 1) & 1) * CB, wpad + (ngrp - 1) * 96);
    } else {
        // slow path (rare): recompute taps per group; global corner reads;
        // 2 barriers per group; single Cs buffer (buffer 0).
        const float* offb = off + (size_t)b * 18 * HW2;
        char* csW = smem + 2 * PB;
        for (int g = 0; g < ngrp; ++g) {
            const unsigned short* gb = acth + bofs + (size_t)g * HW2 * 8;
#pragma unroll
            for (int s = 0; s < 3; ++s) {
                if (!svalid[s]) continue;
                int task = t + s * 256;
                int p = task / 9, k = task - 9 * p;
                int yy = y0 + (p >> 5), xx = x0 + (p & 31);
                float dy = offb[(2 * k) * HW2 + yy * HW + xx];
                float dx = offb[(2 * k + 1) * HW2 + yy * HW + xx];
                float py = (float)(yy + k / 3 - 1) + dy;
                float px = (float)(xx + k % 3 - 1) + dx;
                float fy = floorf(py), fx = floorf(px);
                float wy = py - fy, wx = px - fx;
                int iy = (int)fy, ix = (int)fx;
                float f0 = 0, f1 = 0, f2 = 0, f3 = 0, f4 = 0, f5 = 0, f6 = 0, f7 = 0;
#pragma unroll
                for (int q = 0; q < 4; ++q) {
                    int ddy = q >> 1, ddx = q & 1;
                    int sy = iy + ddy, sx = ix + ddx;
                    float w = (ddy ? wy : 1.f - wy) * (ddx ? wx : 1.f - wx);
                    if (sy < 0 || sy >= HW || sx < 0 || sx >= HW) w = 0.f;
                    int cy = min(max(sy, 0), HW - 1), cx = min(max(sx, 0), HW - 1);
                    uint4 c = *(const uint4*)(gb + (size_t)(cy * HW + cx) * 8);
                    float2 p0 = upk(c.x), p1 = upk(c.y), p2 = upk(c.z), p3 = upk(c.w);
                    f0 += w * p0.x; f1 += w * p0.y; f2 += w * p1.x; f3 += w * p1.y;
                    f4 += w * p2.x; f5 += w * p2.y; f6 += w * p3.x; f7 += w * p3.y;
                }
                uint4 ou;
                ou.x = pk2(f0, f1); ou.y = pk2(f2, f3);
                ou.z = pk2(f4, f5); ou.w = pk2(f6, f7);
                *(uint4*)(csW + csad[s]) = ou;
            }
            __syncthreads();
            mfma_step(csW, wpad + g * 96);
            __syncthreads();
        }
    }

    // ---- epilogue ----
    __syncthreads();   // Es aliases patch/Cs regions
    if (mode == 0) {
        constexpr int ESTR = 136;
#pragma unroll
        for (int m = 0; m < MTW; ++m) {
            int cb = (wv * MTW + m) * 16;
#pragma unroll
            for (int nt = 0; nt < 4; ++nt) {
                int px = nt * 16 + l15;
                int co = cb + quad * 4;
                unsigned int u0 = pk2(lrelu(acc[m][nt][0] + bias[co]),
                                      lrelu(acc[m][nt][1] + bias[co + 1]));
                unsigned int u1 = pk2(lrelu(acc[m][nt][2] + bias[co + 2]),
                                      lrelu(acc[m][nt][3] + bias[co + 3]));
                uint2 u; u.x = u0; u.y = u1;
                *(uint2*)&Es[px * ESTR + co] = u;
            }
        }
        __syncthreads();
        const int ng8 = Cout >> 3;
        unsigned short* ob = outb + (size_t)b * Cout * HW2;
        for (int tt = t; tt < 64 * ng8; tt += 256) {
            int cg = tt >> 6, px = tt & 63;
            int gp2 = (y0 + (px >> 5)) * HW + x0 + (px & 31);
            *(uint4*)(ob + ((size_t)cg * HW2 + gp2) * 8) =
                *(const uint4*)&Es[px * ESTR + cg * 8];
        }
    } else {
        float* of = outf + (size_t)b * Cout * HW2;
#pragma unroll
        for (int m = 0; m < MTW; ++m) {
            int cb = (wv * MTW + m) * 16;
#pragma unroll
            for (int nt = 0; nt < 4; ++nt) {
                int px = nt * 16 + l15;
                int gp2 = (y0 + (px >> 5)) * HW + x0 + (px & 31);
#pragma unroll
                for (int r = 0; r < 4; ++r) {
                    int co = cb + quad * 4 + r;
                    of[(size_t)co * HW2 + gp2] = lrelu(acc[m][nt][r] + bias[co]);
                }
            }
        }
    }
}

// ---------------------------------------------------------------------------
extern "C" void kernel_launch(void* const* d_in, const int* in_sizes, int n_in,
                              void* d_out, int out_size, void* d_ws,
                              size_t ws_size, hipStream_t stream)
{
    const float* x = (const float*)d_in[0];
    const float* p[18];
    for (int i = 0; i < 18; ++i) p[i] = (const float*)d_in[1 + i];

    char* ws = (char*)d_ws;
    unsigned short* A1 = (unsigned short*)ws;              // NHWC8 bf16
    unsigned short* A2 = (unsigned short*)(ws + 16777216);
    float* OFF = (float*)(ws + 33554432);                  // fp32 planar 18ch
    unsigned short* WB = (unsigned short*)(ws + 38273024);

    unsigned short* Wc1 = WB;             // 128 x 768
    unsigned short* Wo1 = Wc1 + 98304;    // 64  x 1536 (18 valid)
    unsigned short* Wd1 = Wo1 + 98304;    // 128 x 1536
    unsigned short* Wc2 = Wd1 + 196608;   // 128 x 1536
    unsigned short* Wo2 = Wc2 + 196608;   // 64  x 1536 (18 valid)
    unsigned short* Wd2 = Wo2 + 98304;    // 128 x 1536
    unsigned short* Wc3 = Wd2 + 196608;   // 64  x 1536
    unsigned short* Wo3 = Wc3 + 98304;    // 64  x 768  (18 valid)
    unsigned short* Wd3 = Wo3 + 49152;    // 64  x 768

    WArgs wa;
    wa.seg[0] = {p[0],  Wc1,  576,  768, 128,  98304};
    wa.seg[1] = {p[2],  Wo1, 1152, 1536,  18,  98304};
    wa.seg[2] = {p[4],  Wd1, 1152, 1536, 128, 196608};
    wa.seg[3] = {p[6],  Wc2, 1152, 1536, 128, 196608};
    wa.seg[4] = {p[8],  Wo2, 1152, 1536,  18,  98304};
    wa.seg[5] = {p[10], Wd2, 1152, 1536, 128, 196608};
    wa.seg[6] = {p[12], Wc3, 1152, 1536,  64,  98304};
    wa.seg[7] = {p[14], Wo3,  576,  768,  18,  49152};
    wa.seg[8] = {p[16], Wd3,  576,  768,  64,  49152};
    wrepack_kernel<<<dim3(768, 9), 256, 0, stream>>>(wa);

    dim3 g(256, 1, 4);      // 2x32 tiles
    // stage 1
    fused_conv<2, 0><<<g, 256, 0, stream>>>(x, Wc1, p[1], A1, nullptr, 64, 128, 0);
    fused_conv<1, 1><<<g, 256, 0, stream>>>(A1, Wo1, p[3], nullptr, OFF, 128, 64, 2);
    fused_deform<2><<<g, 256, 0, stream>>>(A1, OFF, Wd1, p[5], A2, nullptr, 128, 128, 0);
    // stage 2
    fused_conv<2, 1><<<g, 256, 0, stream>>>(A2, Wc2, p[7], A1, nullptr, 128, 128, 0);
    fused_conv<1, 1><<<g, 256, 0, stream>>>(A1, Wo2, p[9], nullptr, OFF, 128, 64, 2);
    fused_deform<2><<<g, 256, 0, stream>>>(A1, OFF, Wd2, p[11], A2, nullptr, 128, 128, 0);
    // stage 3
    fused_conv<1, 1><<<g, 256, 0, stream>>>(A2, Wc3, p[13], A1, nullptr, 128, 64, 0);
    fused_conv<1, 1><<<g, 256, 0, stream>>>(A1, Wo3, p[15], nullptr, OFF, 64, 64, 2);
    fused_deform<1><<<g, 256, 0, stream>>>(A1, OFF, Wd3, p[17], nullptr, (float*)d_out, 64, 64, 1);
}

// Round 12
// 409.596 us; speedup vs baseline: 2.1634x; 1.0270x over previous
//
#include <hip/hip_runtime.h>
#include <hip/hip_bf16.h>

#define HW 128
#define HW2 16384
#define NEG 0.2f

typedef __attribute__((ext_vector_type(8))) short short8;
typedef __attribute__((ext_vector_type(4))) float f32x4;
typedef __attribute__((ext_vector_type(2))) float f32x2;

__device__ __forceinline__ float lrelu(float v) { return v >= 0.f ? v : NEG * v; }
__device__ __forceinline__ unsigned short f2bf(float f) {
    unsigned int u = __float_as_uint(f);
    u = (u + 0x7fffu + ((u >> 16) & 1u)) >> 16;
    return (unsigned short)u;
}
__device__ __forceinline__ unsigned int pk2(float a, float b) {
    __hip_bfloat162 h = __float22bfloat162_rn(float2{a, b});
    return *(unsigned int*)&h;
}
__device__ __forceinline__ float2 upk(unsigned int u) {
    return float2{__uint_as_float(u << 16), __uint_as_float(u & 0xffff0000u)};
}
__device__ __forceinline__ f32x2 upkv(unsigned int u) {
    f32x2 r;
    r.x = __uint_as_float(u << 16);
    r.y = __uint_as_float(u & 0xffff0000u);
    return r;
}

// ---------------------------------------------------------------------------
// Weight repack fp32 [M][Cin][3][3] -> bf16 [Mpad][Kpad], Kpad=(Cin/8)*96,
// k-order TAP-MAJOR: k = g*96 + tap*8 + cl, taps 9..11 zero, rows>=validM zero.
// ---------------------------------------------------------------------------
struct WSeg { const float* s; unsigned short* d; int K9; int Kpad; int validM; int n; };
struct WArgs { WSeg seg[9]; };

__global__ void wrepack_kernel(WArgs a)
{
    const WSeg sg = a.seg[blockIdx.y];
    int i = blockIdx.x * 256 + threadIdx.x;
    if (i >= sg.n) return;
    int co = i / sg.Kpad, r = i - co * sg.Kpad;
    int g = r / 96, q = r - g * 96;
    int tap = q >> 3, cl = q & 7;
    unsigned short v = 0;
    if (co < sg.validM && tap < 9)
        v = f2bf(sg.s[(size_t)co * sg.K9 + (g * 8 + cl) * 9 + tap]);
    sg.d[i] = v;
}

// ---------------------------------------------------------------------------
// Fused plain conv (N=64 tile, 2x32), single barrier per group, A-prefetch:
// MFMA(g) uses A-regs loaded in iteration g-1 (no L2 stall after barrier).
// ---------------------------------------------------------------------------
template <int MTW, int SRCF>
__global__ __launch_bounds__(256, 4) void fused_conv(
    const void* __restrict__ actv, const unsigned short* __restrict__ wpad,
    const float* __restrict__ bias, unsigned short* __restrict__ outb,
    float* __restrict__ outf, int Cin, int Cout, int mode)
{
    constexpr int PB = 136 * 16;                 // 2176 B per patch buffer
    constexpr int SMB = 64 * 136 * 2;            // Es (17408) > 2*PB
    __shared__ char smem[SMB];
    unsigned short* Es = (unsigned short*)smem;

    const int t = threadIdx.x;
    const int tile = blockIdx.x, b = blockIdx.z;
    const int lane = t & 63, wv = t >> 6, quad = lane >> 4, l15 = lane & 15;
    const int y0 = (tile >> 2) * 2, x0 = (tile & 3) * 32;
    const int Kpad = (Cin >> 3) * 96;
    const int ngrp = Cin >> 3;

    const int pr = t / 34, pc = t - 34 * pr;
    const int gy = y0 - 1 + pr, gx = x0 - 1 + pc;
    const bool pok = (t < 136) && gy >= 0 && gy < HW && gx >= 0 && gx < HW;
    const int gp = pok ? gy * HW + gx : 0;

    const float* actf = (const float*)actv;
    const unsigned short* acth = (const unsigned short*)actv;
    const size_t bofs = (size_t)b * Cin * HW2;

    int baddr[3][4];
#pragma unroll
    for (int st = 0; st < 3; ++st) {
        int tap = st * 4 + quad; tap = tap > 8 ? 8 : tap;
        int ky = (tap * 11) >> 5, kx = tap - 3 * ky;
#pragma unroll
        for (int nt = 0; nt < 4; ++nt) {
            int p = nt * 16 + l15, ly = p >> 5, lx = p & 31;
            baddr[st][nt] = ((ly + ky) * 34 + lx + kx) * 16;
        }
    }
    size_t aoff[MTW];
#pragma unroll
    for (int m = 0; m < MTW; ++m)
        aoff[m] = (size_t)((wv * MTW + m) * 16 + l15) * Kpad + quad * 8;

    f32x4 acc[MTW][4];
#pragma unroll
    for (int m = 0; m < MTW; ++m)
#pragma unroll
        for (int nt = 0; nt < 4; ++nt) acc[m][nt] = (f32x4)(0.f);

    auto load_grp = [&](int g) -> uint4 {
        uint4 u; u.x = u.y = u.z = u.w = 0;
        if (!pok) return u;
        if (SRCF == 1) {
            u = *(const uint4*)(acth + bofs + ((size_t)g * HW2 + gp) * 8);
        } else {
            const float* pl = actf + bofs + (size_t)(g * 8) * HW2 + gp;
            float v0 = pl[0], v1 = pl[HW2], v2 = pl[2 * HW2], v3 = pl[3 * HW2];
            float v4 = pl[4 * HW2], v5 = pl[5 * HW2], v6 = pl[6 * HW2], v7 = pl[7 * HW2];
            u.x = pk2(v0, v1); u.y = pk2(v2, v3);
            u.z = pk2(v4, v5); u.w = pk2(v6, v7);
        }
        return u;
    };

    short8 apre[MTW][3];
    auto loadA = [&](int g) {
#pragma unroll
        for (int st = 0; st < 3; ++st)
#pragma unroll
            for (int m = 0; m < MTW; ++m)
                apre[m][st] = *(const short8*)(wpad + (size_t)g * 96 + aoff[m] + st * 32);
    };

    uint4 cur = load_grp(0);
    if (t < 136) *(uint4*)(smem + t * 16) = cur;          // patch buf 0
    loadA(0);
    if (ngrp > 1) cur = load_grp(1);
    __syncthreads();

    for (int g = 0; g < ngrp; ++g) {
        char* pb = smem + (g & 1) * PB;
#pragma unroll
        for (int st = 0; st < 3; ++st) {
            short8 bfr[4];
#pragma unroll
            for (int nt = 0; nt < 4; ++nt)
                bfr[nt] = *(const short8*)(pb + baddr[st][nt]);
#pragma unroll
            for (int m = 0; m < MTW; ++m) {
                short8 a = apre[m][st];
#pragma unroll
                for (int nt = 0; nt < 4; ++nt)
                    acc[m][nt] = __builtin_amdgcn_mfma_f32_16x16x32_bf16(
                        a, bfr[nt], acc[m][nt], 0, 0, 0);
            }
        }
        if (g + 1 < ngrp) {
            if (t < 136) *(uint4*)(smem + ((g + 1) & 1) * PB + t * 16) = cur;
            loadA(g + 1);
            if (g + 2 < ngrp) cur = load_grp(g + 2);
        }
        __syncthreads();
    }

    if (mode == 0) {
        constexpr int ESTR = 136;
#pragma unroll
        for (int m = 0; m < MTW; ++m) {
            int cb = (wv * MTW + m) * 16;
#pragma unroll
            for (int nt = 0; nt < 4; ++nt) {
                int px = nt * 16 + l15;
                int co = cb + quad * 4;
                unsigned int u0 = pk2(lrelu(acc[m][nt][0] + bias[co]),
                                      lrelu(acc[m][nt][1] + bias[co + 1]));
                unsigned int u1 = pk2(lrelu(acc[m][nt][2] + bias[co + 2]),
                                      lrelu(acc[m][nt][3] + bias[co + 3]));
                uint2 u; u.x = u0; u.y = u1;
                *(uint2*)&Es[px * ESTR + co] = u;
            }
        }
        __syncthreads();
        const int ng8 = Cout >> 3;
        unsigned short* ob = outb + (size_t)b * Cout * HW2;
        for (int tt = t; tt < 64 * ng8; tt += 256) {
            int cg = tt >> 6, px = tt & 63;
            int gp2 = (y0 + (px >> 5)) * HW + x0 + (px & 31);
            *(uint4*)(ob + ((size_t)cg * HW2 + gp2) * 8) =
                *(const uint4*)&Es[px * ESTR + cg * 8];
        }
    } else {
        float* of = outf + (size_t)b * 18 * HW2;
#pragma unroll
        for (int m = 0; m < MTW; ++m) {
            int cb = (wv * MTW + m) * 16;
#pragma unroll
            for (int nt = 0; nt < 4; ++nt) {
                int px = nt * 16 + l15;
                int gp2 = (y0 + (px >> 5)) * HW + x0 + (px & 31);
#pragma unroll
                for (int r = 0; r < 4; ++r) {
                    int co = cb + quad * 4 + r;
                    if (co < 18)
                        of[(size_t)co * HW2 + gp2] = acc[m][nt][r] + bias[co];
                }
            }
        }
    }
}

// ---------------------------------------------------------------------------
// Fused deformable conv, N=64 (2x32 px), software-pipelined (one barrier per
// group) + A-register prefetch + packed (v_pk_fma_f32) bilinear col-build +
// PATW=42 (row stride = 8 banks mod 32, fewer conflicts). LDS 40.1 KB.
// mode 0: NHWC8 bf16 out + leaky; mode 1: planar fp32 out + leaky.
// ---------------------------------------------------------------------------
template <int MTW>
__global__ __launch_bounds__(256, 4) void fused_deform(
    const unsigned short* __restrict__ acth, const float* __restrict__ off,
    const unsigned short* __restrict__ wpad, const float* __restrict__ bias,
    unsigned short* __restrict__ outb, float* __restrict__ outf,
    int Cin, int Cout, int mode)
{
    constexpr int PATW = 42, PATP = 420;
    constexpr int CSTR = 104;
    constexpr int PB = PATP * 16;                 // 6720 B
    constexpr int CB = 64 * CSTR * 2;             // 13312 B
    constexpr int SMB = 2 * PB + 2 * CB;          // 40064 B
    __shared__ char smem[SMB];
    unsigned short* Es = (unsigned short*)smem;   // epilogue alias (17408 B)

    const int t = threadIdx.x;
    const int tile = blockIdx.x, b = blockIdx.z;
    const int lane = t & 63, wv = t >> 6, quad = lane >> 4, l15 = lane & 15;
    const int y0 = (tile >> 2) * 2, x0 = (tile & 3) * 32;
    const int Kpad = (Cin >> 3) * 96;
    const int ngrp = Cin >> 3;
    const int py0 = y0 - 4, px0 = x0 - 4;

    // zero Cs k-pad [72,96) in BOTH buffers: 2 bufs x 64 rows x 3 uint4 = 384
    for (int i = t; i < 384; i += 256) {
        int bu = i / 192;
        int ii = i - 192 * bu;
        int p = ii / 3, j = ii - 3 * p;
        uint4 z; z.x = z.y = z.z = z.w = 0;
        *(uint4*)(smem + 2 * PB + bu * CB + (p * CSTR + 72 + j * 8) * 2) = z;
    }

    // ---- phase 0: fast-path tap params (slots t, t+256, t+512) ----
    float w00[3], w01[3], w10[3], w11[3];
    int pbase[3], csad[3], svalid[3];
    int allin = 1;
    {
        const float* offb = off + (size_t)b * 18 * HW2;
#pragma unroll
        for (int s = 0; s < 3; ++s) {
            int task = t + s * 256;
            svalid[s] = task < 576;
            int task2 = svalid[s] ? task : 0;
            int p = task2 / 9, k = task2 - 9 * p;
            int yy = y0 + (p >> 5), xx = x0 + (p & 31);
            float dy = offb[(2 * k) * HW2 + yy * HW + xx];
            float dx = offb[(2 * k + 1) * HW2 + yy * HW + xx];
            float py = (float)(yy + k / 3 - 1) + dy;
            float px = (float)(xx + k % 3 - 1) + dx;
            float fy = floorf(py), fx = floorf(px);
            float wy = py - fy, wx = px - fx;
            int iy = (int)fy, ix = (int)fx;
            w00[s] = (1.f - wy) * (1.f - wx);
            w01[s] = (1.f - wy) * wx;
            w10[s] = wy * (1.f - wx);
            w11[s] = wy * wx;
            pbase[s] = ((iy - py0) * PATW + (ix - px0)) * 16;   // bytes
            csad[s] = (p * CSTR + k * 8) * 2;                   // bytes
            bool ip = iy >= py0 && iy + 1 <= y0 + 5 && ix >= px0 && ix + 1 <= x0 + 36;
            if (!ip) allin = 0;
        }
    }
    const int fast = __syncthreads_and(allin);

    // staging: slot0 = t (<420 always), slot1 = t+256 (t<164)
    const int r0 = t / PATW, c0_ = t - PATW * r0;
    const int gy0_ = py0 + r0, gx0_ = px0 + c0_;
    const bool ok0 = gy0_ >= 0 && gy0_ < HW && gx0_ >= 0 && gx0_ < HW;
    const int go0 = ok0 ? gy0_ * HW + gx0_ : 0;
    const int i1 = t + 256;
    const bool has1 = i1 < PATP;
    const int r1 = i1 / PATW, c1_ = i1 - PATW * r1;
    const int gy1_ = py0 + r1, gx1_ = px0 + c1_;
    const bool ok1 = has1 && gy1_ >= 0 && gy1_ < HW && gx1_ >= 0 && gx1_ < HW;
    const int go1 = ok1 ? gy1_ * HW + gx1_ : 0;

    const size_t bofs = (size_t)b * Cin * HW2;

    size_t aoff[MTW];
#pragma unroll
    for (int m = 0; m < MTW; ++m)
        aoff[m] = (size_t)((wv * MTW + m) * 16 + l15) * Kpad + quad * 8;
    const int bb0 = l15 * (CSTR * 2) + quad * 16;   // B-frag byte base in Cs

    f32x4 acc[MTW][4];
#pragma unroll
    for (int m = 0; m < MTW; ++m)
#pragma unroll
        for (int nt = 0; nt < 4; ++nt) acc[m][nt] = (f32x4)(0.f);

    short8 apre[MTW][3];
    auto loadA = [&](int g) {
#pragma unroll
        for (int st = 0; st < 3; ++st)
#pragma unroll
            for (int m = 0; m < MTW; ++m)
                apre[m][st] = *(const short8*)(wpad + (size_t)g * 96 + aoff[m] + st * 32);
    };

    auto mfma_pre = [&](const char* cs) {
#pragma unroll
        for (int st = 0; st < 3; ++st) {
            short8 bfr[4];
#pragma unroll
            for (int nt = 0; nt < 4; ++nt)
                bfr[nt] = *(const short8*)(cs + bb0 + nt * 16 * (CSTR * 2) + st * 64);
#pragma unroll
            for (int m = 0; m < MTW; ++m) {
                short8 a = apre[m][st];
#pragma unroll
                for (int nt = 0; nt < 4; ++nt)
                    acc[m][nt] = __builtin_amdgcn_mfma_f32_16x16x32_bf16(
                        a, bfr[nt], acc[m][nt], 0, 0, 0);
            }
        }
    };

    if (fast) {
        uint4 u0, u1;
        u0.x = u0.y = u0.z = u0.w = 0; u1 = u0;
        if (ok0) u0 = *(const uint4*)(acth + bofs + (size_t)go0 * 8);
        if (ok1) u1 = *(const uint4*)(acth + bofs + (size_t)go1 * 8);
        *(uint4*)(smem + t * 16) = u0;
        if (has1) *(uint4*)(smem + i1 * 16) = u1;
        if (ngrp > 1) {
            u0.x = u0.y = u0.z = u0.w = 0; u1 = u0;
            if (ok0) u0 = *(const uint4*)(acth + bofs + ((size_t)HW2 + go0) * 8);
            if (ok1) u1 = *(const uint4*)(acth + bofs + ((size_t)HW2 + go1) * 8);
        }
        __syncthreads();

        for (int g = 0; g < ngrp; ++g) {
            const char* pb = smem + (g & 1) * PB;
            char* csW = smem + 2 * PB + (g & 1) * CB;

            // (a) MFMA for previous group (A already in regs)
            if (g > 0)
                mfma_pre(smem + 2 * PB + ((g - 1) & 1) * CB);

            // (b) col build g -> Cs[g&1] (packed f32x2 math)
#pragma unroll
            for (int s = 0; s < 3; ++s) {
                if (!svalid[s]) continue;
                const char* base = pb + pbase[s];
                uint4 c00 = *(const uint4*)base;
                uint4 c01 = *(const uint4*)(base + 16);
                uint4 c10 = *(const uint4*)(base + PATW * 16);
                uint4 c11 = *(const uint4*)(base + PATW * 16 + 16);
                f32x2 vw0 = (f32x2)(w00[s]), vw1 = (f32x2)(w01[s]);
                f32x2 vw2 = (f32x2)(w10[s]), vw3 = (f32x2)(w11[s]);
                f32x2 a0 = vw0 * upkv(c00.x) + vw1 * upkv(c01.x)
                         + vw2 * upkv(c10.x) + vw3 * upkv(c11.x);
                f32x2 a1 = vw0 * upkv(c00.y) + vw1 * upkv(c01.y)
                         + vw2 * upkv(c10.y) + vw3 * upkv(c11.y);
                f32x2 a2 = vw0 * upkv(c00.z) + vw1 * upkv(c01.z)
                         + vw2 * upkv(c10.z) + vw3 * upkv(c11.z);
                f32x2 a3 = vw0 * upkv(c00.w) + vw1 * upkv(c01.w)
                         + vw2 * upkv(c10.w) + vw3 * upkv(c11.w);
                uint4 ou;
                ou.x = pk2(a0.x, a0.y); ou.y = pk2(a1.x, a1.y);
                ou.z = pk2(a2.x, a2.y); ou.w = pk2(a3.x, a3.y);
                *(uint4*)(csW + csad[s]) = ou;
            }

            // (c) write patch g+1; (d) prefetch A(g); (e) load act g+2
            if (g + 1 < ngrp) {
                char* pn = smem + ((g + 1) & 1) * PB;
                *(uint4*)(pn + t * 16) = u0;
                if (has1) *(uint4*)(pn + i1 * 16) = u1;
            }
            loadA(g);
            if (g + 2 < ngrp) {
                u0.x = u0.y = u0.z = u0.w = 0; u1 = u0;
                if (ok0) u0 = *(const uint4*)(acth + bofs +
                                              ((size_t)(g + 2) * HW2 + go0) * 8);
                if (ok1) u1 = *(const uint4*)(acth + bofs +
                                              ((size_t)(g + 2) * HW2 + go1) * 8);
            }
            __syncthreads();
        }
        // final group's MFMA (apre = A(ngrp-1))
        mfma_pre(smem + 2 * PB + ((ngrp - 1) & 1) * CB);
    } else {
        // slow path (rare): recompute taps per group; global corner reads;
        // 2 barriers per group; single Cs buffer (buffer 0).
        const float* offb = off + (size_t)b * 18 * HW2;
        char* csW = smem + 2 * PB;
        for (int g = 0; g < ngrp; ++g) {
            const unsigned short* gb = acth + bofs + (size_t)g * HW2 * 8;
#pragma unroll
            for (int s = 0; s < 3; ++s) {
                if (!svalid[s]) continue;
                int task = t + s * 256;
                int p = task / 9, k = task - 9 * p;
                int yy = y0 + (p >> 5), xx = x0 + (p & 31);
                float dy = offb[(2 * k) * HW2 + yy * HW + xx];
                float dx = offb[(2 * k + 1) * HW2 + yy * HW + xx];
                float py = (float)(yy + k / 3 - 1) + dy;
                float px = (float)(xx + k % 3 - 1) + dx;
                float fy = floorf(py), fx = floorf(px);
                float wy = py - fy, wx = px - fx;
                int iy = (int)fy, ix = (int)fx;
                float f0 = 0, f1 = 0, f2 = 0, f3 = 0, f4 = 0, f5 = 0, f6 = 0, f7 = 0;
#pragma unroll
                for (int q = 0; q < 4; ++q) {
                    int ddy = q >> 1, ddx = q & 1;
                    int sy = iy + ddy, sx = ix + ddx;
                    float w = (ddy ? wy : 1.f - wy) * (ddx ? wx : 1.f - wx);
                    if (sy < 0 || sy >= HW || sx < 0 || sx >= HW) w = 0.f;
                    int cy = min(max(sy, 0), HW - 1), cx = min(max(sx, 0), HW - 1);
                    uint4 c = *(const uint4*)(gb + (size_t)(cy * HW + cx) * 8);
                    float2 p0 = upk(c.x), p1 = upk(c.y), p2 = upk(c.z), p3 = upk(c.w);
                    f0 += w * p0.x; f1 += w * p0.y; f2 += w * p1.x; f3 += w * p1.y;
                    f4 += w * p2.x; f5 += w * p2.y; f6 += w * p3.x; f7 += w * p3.y;
                }
                uint4 ou;
                ou.x = pk2(f0, f1); ou.y = pk2(f2, f3);
                ou.z = pk2(f4, f5); ou.w = pk2(f6, f7);
                *(uint4*)(csW + csad[s]) = ou;
            }
            __syncthreads();
            loadA(g);
            mfma_pre(csW);
            __syncthreads();
        }
    }

    // ---- epilogue ----
    __syncthreads();   // Es aliases patch/Cs regions
    if (mode == 0) {
        constexpr int ESTR = 136;
#pragma unroll
        for (int m = 0; m < MTW; ++m) {
            int cb = (wv * MTW + m) * 16;
#pragma unroll
            for (int nt = 0; nt < 4; ++nt) {
                int px = nt * 16 + l15;
                int co = cb + quad * 4;
                unsigned int u0 = pk2(lrelu(acc[m][nt][0] + bias[co]),
                                      lrelu(acc[m][nt][1] + bias[co + 1]));
                unsigned int u1 = pk2(lrelu(acc[m][nt][2] + bias[co + 2]),
                                      lrelu(acc[m][nt][3] + bias[co + 3]));
                uint2 u; u.x = u0; u.y = u1;
                *(uint2*)&Es[px * ESTR + co] = u;
            }
        }
        __syncthreads();
        const int ng8 = Cout >> 3;
        unsigned short* ob = outb + (size_t)b * Cout * HW2;
        for (int tt = t; tt < 64 * ng8; tt += 256) {
            int cg = tt >> 6, px = tt & 63;
            int gp2 = (y0 + (px >> 5)) * HW + x0 + (px & 31);
            *(uint4*)(ob + ((size_t)cg * HW2 + gp2) * 8) =
                *(const uint4*)&Es[px * ESTR + cg * 8];
        }
    } else {
        float* of = outf + (size_t)b * Cout * HW2;
#pragma unroll
        for (int m = 0; m < MTW; ++m) {
            int cb = (wv * MTW + m) * 16;
#pragma unroll
            for (int nt = 0; nt < 4; ++nt) {
                int px = nt * 16 + l15;
                int gp2 = (y0 + (px >> 5)) * HW + x0 + (px & 31);
#pragma unroll
                for (int r = 0; r < 4; ++r) {
                    int co = cb + quad * 4 + r;
                    of[(size_t)co * HW2 + gp2] = lrelu(acc[m][nt][r] + bias[co]);
                }
            }
        }
    }
}

// ---------------------------------------------------------------------------
extern "C" void kernel_launch(void* const* d_in, const int* in_sizes, int n_in,
                              void* d_out, int out_size, void* d_ws,
                              size_t ws_size, hipStream_t stream)
{
    const float* x = (const float*)d_in[0];
    const float* p[18];
    for (int i = 0; i < 18; ++i) p[i] = (const float*)d_in[1 + i];

    char* ws = (char*)d_ws;
    unsigned short* A1 = (unsigned short*)ws;              // NHWC8 bf16
    unsigned short* A2 = (unsigned short*)(ws + 16777216);
    float* OFF = (float*)(ws + 33554432);                  // fp32 planar 18ch
    unsigned short* WB = (unsigned short*)(ws + 38273024);

    unsigned short* Wc1 = WB;             // 128 x 768
    unsigned short* Wo1 = Wc1 + 98304;    // 64  x 1536 (18 valid)
    unsigned short* Wd1 = Wo1 + 98304;    // 128 x 1536
    unsigned short* Wc2 = Wd1 + 196608;   // 128 x 1536
    unsigned short* Wo2 = Wc2 + 196608;   // 64  x 1536 (18 valid)
    unsigned short* Wd2 = Wo2 + 98304;    // 128 x 1536
    unsigned short* Wc3 = Wd2 + 196608;   // 64  x 1536
    unsigned short* Wo3 = Wc3 + 98304;    // 64  x 768  (18 valid)
    unsigned short* Wd3 = Wo3 + 49152;    // 64  x 768

    WArgs wa;
    wa.seg[0] = {p[0],  Wc1,  576,  768, 128,  98304};
    wa.seg[1] = {p[2],  Wo1, 1152, 1536,  18,  98304};
    wa.seg[2] = {p[4],  Wd1, 1152, 1536, 128, 196608};
    wa.seg[3] = {p[6],  Wc2, 1152, 1536, 128, 196608};
    wa.seg[4] = {p[8],  Wo2, 1152, 1536,  18,  98304};
    wa.seg[5] = {p[10], Wd2, 1152, 1536, 128, 196608};
    wa.seg[6] = {p[12], Wc3, 1152, 1536,  64,  98304};
    wa.seg[7] = {p[14], Wo3,  576,  768,  18,  49152};
    wa.seg[8] = {p[16], Wd3,  576,  768,  64,  49152};
    wrepack_kernel<<<dim3(768, 9), 256, 0, stream>>>(wa);

    dim3 g(256, 1, 4);      // 2x32 tiles
    // stage 1
    fused_conv<2, 0><<<g, 256, 0, stream>>>(x, Wc1, p[1], A1, nullptr, 64, 128, 0);
    fused_conv<1, 1><<<g, 256, 0, stream>>>(A1, Wo1, p[3], nullptr, OFF, 128, 64, 2);
    fused_deform<2><<<g, 256, 0, stream>>>(A1, OFF, Wd1, p[5], A2, nullptr, 128, 128, 0);
    // stage 2
    fused_conv<2, 1><<<g, 256, 0, stream>>>(A2, Wc2, p[7], A1, nullptr, 128, 128, 0);
    fused_conv<1, 1><<<g, 256, 0, stream>>>(A1, Wo2, p[9], nullptr, OFF, 128, 64, 2);
    fused_deform<2><<<g, 256, 0, stream>>>(A1, OFF, Wd2, p[11], A2, nullptr, 128, 128, 0);
    // stage 3
    fused_conv<1, 1><<<g, 256, 0, stream>>>(A2, Wc3, p[13], A1, nullptr, 128, 64, 0);
    fused_conv<1, 1><<<g, 256, 0, stream>>>(A1, Wo3, p[15], nullptr, OFF, 64, 64, 2);
    fused_deform<1><<<g, 256, 0, stream>>>(A1, OFF, Wd3, p[17], nullptr, (float*)d_out, 64, 64, 1);
}